// Round 4
// baseline (395.238 us; speedup 1.0000x reference)
//
#include <hip/hip_runtime.h>
#include <hip/hip_bf16.h>
#include <math.h>

#define BB 4
#define SS 2048
#define DDIM 1024
#define HH 16
#define DH 64

typedef unsigned short ushort_t;
typedef __attribute__((ext_vector_type(8))) short short8;
typedef __attribute__((ext_vector_type(4))) float floatx4;
typedef __attribute__((ext_vector_type(4))) unsigned int uintx4;

__device__ __forceinline__ float bf2f(ushort_t u) {
    unsigned int x = ((unsigned int)u) << 16;
    return __builtin_bit_cast(float, x);
}
__device__ __forceinline__ ushort_t f2bf(float f) {
    unsigned int x = __builtin_bit_cast(unsigned int, f);
    unsigned int r = (x + 0x7FFFu + ((x >> 16) & 1u)) >> 16;
    return (ushort_t)r;
}

__device__ __forceinline__ void load_lds16(const ushort_t* g, void* l) {
    __builtin_amdgcn_global_load_lds((const __attribute__((address_space(1))) void*)g,
                                     (__attribute__((address_space(3))) void*)l, 16, 0, 0);
}

// ---------------- fused prep: cast x, cast 6 weights, qg matvec ----------------
__global__ __launch_bounds__(256) void prep_kernel(
    const float* __restrict__ x,
    const float* __restrict__ w0, const float* __restrict__ w1, const float* __restrict__ w2,
    const float* __restrict__ w3, const float* __restrict__ w4, const float* __restrict__ w5,
    const float* __restrict__ Wqg, const float* __restrict__ bqg,
    ushort_t* __restrict__ hbf, ushort_t* __restrict__ wbf, float* __restrict__ qg) {
    int bid = blockIdx.x;
    int tid = threadIdx.x;
    if (bid < 32768) {
        // cast x [S,B,D] -> hbf [B,S,D]
        int id = bid * 256 + tid;
        int d = id & (DDIM - 1);
        int s = (id >> 10) & (SS - 1);
        int b = id >> 21;
        hbf[id] = f2bf(x[(s * BB + b) * DDIM + d]);
    } else if (bid < 57344) {
        int id = (bid - 32768) * 256 + tid;          // 6 * 1048576
        int which = id >> 20;
        int r = id & 0xFFFFF;
        const float* src = which == 0 ? w0 : which == 1 ? w1 : which == 2 ? w2
                          : which == 3 ? w3 : which == 4 ? w4 : w5;
        wbf[id] = f2bf(src[r]);
    } else {
        // qg: (x[0,b,:] @ Wqg^T + bqg) * scale  -> 4096 wave-jobs
        int wave = ((bid - 57344) * 256 + tid) >> 6;
        int lane = tid & 63;
        int b = wave >> 10;
        int n = wave & 1023;
        const float* xr = x + b * DDIM;
        const float* wr = Wqg + n * DDIM;
        float acc = 0.f;
        for (int kk = lane; kk < DDIM; kk += 64) acc += xr[kk] * wr[kk];
        for (int off = 32; off > 0; off >>= 1) acc += __shfl_down(acc, off, 64);
        if (lane == 0) qg[b * DDIM + n] = (acc + bqg[n]) * 0.125f;
    }
}

// ---------------- fused qkv/kg/vg GEMM: 128x128 tile, global_load_lds, xor-swizzle ----------------
__global__ __launch_bounds__(256) void qkv_gemm_kernel(
    const ushort_t* __restrict__ hbf, const ushort_t* __restrict__ wbf,
    const float* __restrict__ bq, const float* __restrict__ bk, const float* __restrict__ bv,
    const float* __restrict__ bkg, const float* __restrict__ bvg,
    ushort_t* __restrict__ qb, ushort_t* __restrict__ kb, ushort_t* __restrict__ vtb,
    ushort_t* __restrict__ kgb, ushort_t* __restrict__ vgb) {
    __shared__ ushort_t As[128 * 64];
    __shared__ ushort_t Bs[128 * 64];
    int Mbase = blockIdx.x * 128;
    int Nbase = blockIdx.y * 128;
    int tid = threadIdx.x;
    int wave = tid >> 6, lane = tid & 63, quad = lane >> 4, l16 = lane & 15;
    int mbase = (wave & 1) * 64, nbase = (wave >> 1) * 64;
    int lrow = lane >> 3, scol = ((lane & 7) ^ lrow) * 8;   // swizzled global column

    const ushort_t* Ag = hbf + (size_t)(Mbase + wave * 32 + lrow) * DDIM + scol;
    const ushort_t* Bg = wbf + (size_t)(Nbase + wave * 32 + lrow) * DDIM + scol;

    floatx4 acc[4][4];
    floatx4 z4 = {0.f, 0.f, 0.f, 0.f};
#pragma unroll
    for (int i = 0; i < 4; ++i)
#pragma unroll
        for (int j = 0; j < 4; ++j) acc[i][j] = z4;

    for (int kk = 0; kk < DDIM; kk += 64) {
        __syncthreads();
#pragma unroll
        for (int j = 0; j < 4; ++j) {
            load_lds16(Ag + kk + (size_t)j * 8 * DDIM, &As[(wave * 32 + j * 8) * 64]);
            load_lds16(Bg + kk + (size_t)j * 8 * DDIM, &Bs[(wave * 32 + j * 8) * 64]);
        }
        __syncthreads();
#pragma unroll
        for (int ks = 0; ks < 2; ++ks) {
            int swc = ((ks * 4 + quad) ^ (l16 & 7)) * 8;
            short8 a[4], b[4];
#pragma unroll
            for (int mt = 0; mt < 4; ++mt)
                a[mt] = *(const short8*)(&As[(mbase + mt * 16 + l16) * 64 + swc]);
#pragma unroll
            for (int nt = 0; nt < 4; ++nt)
                b[nt] = *(const short8*)(&Bs[(nbase + nt * 16 + l16) * 64 + swc]);
#pragma unroll
            for (int mt = 0; mt < 4; ++mt)
#pragma unroll
                for (int nt = 0; nt < 4; ++nt)
                    acc[mt][nt] = __builtin_amdgcn_mfma_f32_16x16x32_bf16(a[mt], b[nt], acc[mt][nt], 0, 0, 0);
        }
    }

    int which = Nbase >> 10;
    float scale = (which == 0) ? 0.125f : 1.0f;
    const float* bias = which == 0 ? bq : which == 1 ? bk : which == 2 ? bv : which == 3 ? bkg : bvg;
#pragma unroll
    for (int nt = 0; nt < 4; ++nt) {
        int n = Nbase + nbase + nt * 16 + l16;
        int hd = n & 1023;
        int hh = hd >> 6, d = hd & 63;
        float bsv = bias[hd];
#pragma unroll
        for (int mt = 0; mt < 4; ++mt) {
#pragma unroll
            for (int r = 0; r < 4; ++r) {
                int m = Mbase + mbase + mt * 16 + quad * 4 + r;
                int b = m >> 11, s = m & 2047;
                float val = (acc[mt][nt][r] + bsv) * scale;
                ushort_t o = f2bf(val);
                if (which == 2) {
                    vtb[((size_t)(b * HH + hh) * DH + d) * SS + s] = o;
                } else {
                    ushort_t* dst = which == 0 ? qb : which == 1 ? kb : which == 3 ? kgb : vgb;
                    dst[((size_t)(b * HH + hh) * SS + s) * DH + d] = o;
                }
            }
        }
    }
}

// ---------------- output GEMM (attn @ Wo^T + bo + residual), 128x128 tile, swizzled ----------------
__global__ __launch_bounds__(256) void out_gemm_kernel(
    const ushort_t* __restrict__ abf, const ushort_t* __restrict__ wo,
    const float* __restrict__ bo, const float* __restrict__ x, float* __restrict__ ypre) {
    __shared__ ushort_t As[128 * 64];
    __shared__ ushort_t Bs[128 * 64];
    int Mbase = blockIdx.x * 128;
    int Nbase = blockIdx.y * 128;
    int tid = threadIdx.x;
    int wave = tid >> 6, lane = tid & 63, quad = lane >> 4, l16 = lane & 15;
    int mbase = (wave & 1) * 64, nbase = (wave >> 1) * 64;
    int lrow = lane >> 3, scol = ((lane & 7) ^ lrow) * 8;

    const ushort_t* Ag = abf + (size_t)(Mbase + wave * 32 + lrow) * DDIM + scol;
    const ushort_t* Bg = wo + (size_t)(Nbase + wave * 32 + lrow) * DDIM + scol;

    floatx4 acc[4][4];
    floatx4 z4 = {0.f, 0.f, 0.f, 0.f};
#pragma unroll
    for (int i = 0; i < 4; ++i)
#pragma unroll
        for (int j = 0; j < 4; ++j) acc[i][j] = z4;

    for (int kk = 0; kk < DDIM; kk += 64) {
        __syncthreads();
#pragma unroll
        for (int j = 0; j < 4; ++j) {
            load_lds16(Ag + kk + (size_t)j * 8 * DDIM, &As[(wave * 32 + j * 8) * 64]);
            load_lds16(Bg + kk + (size_t)j * 8 * DDIM, &Bs[(wave * 32 + j * 8) * 64]);
        }
        __syncthreads();
#pragma unroll
        for (int ks = 0; ks < 2; ++ks) {
            int swc = ((ks * 4 + quad) ^ (l16 & 7)) * 8;
            short8 a[4], b[4];
#pragma unroll
            for (int mt = 0; mt < 4; ++mt)
                a[mt] = *(const short8*)(&As[(mbase + mt * 16 + l16) * 64 + swc]);
#pragma unroll
            for (int nt = 0; nt < 4; ++nt)
                b[nt] = *(const short8*)(&Bs[(nbase + nt * 16 + l16) * 64 + swc]);
#pragma unroll
            for (int mt = 0; mt < 4; ++mt)
#pragma unroll
                for (int nt = 0; nt < 4; ++nt)
                    acc[mt][nt] = __builtin_amdgcn_mfma_f32_16x16x32_bf16(a[mt], b[nt], acc[mt][nt], 0, 0, 0);
        }
    }

#pragma unroll
    for (int nt = 0; nt < 4; ++nt) {
        int n = Nbase + nbase + nt * 16 + l16;
        float bsv = bo[n];
#pragma unroll
        for (int mt = 0; mt < 4; ++mt) {
#pragma unroll
            for (int r = 0; r < 4; ++r) {
                int m = Mbase + mbase + mt * 16 + quad * 4 + r;
                int b = m >> 11, s = m & 2047;
                ypre[(size_t)m * DDIM + n] = acc[mt][nt][r] + bsv + x[(size_t)(s * BB + b) * DDIM + n];
            }
        }
    }
}

// ---------------- local (windowed) attention ----------------
// block: (qblk, h, b); 64 queries; window = 320 keys; 256 threads.
// LDS arena (53504 B, 3 blocks/CU):
//   0..1024      gs/pg/v0/k0
//   1024..41984  Kw [320][64] swizzled        (phase A)
//   1024..43008  P  [64][328]                 (phase B, aliases Kw)
//   43008..51200 Qs [64][64] swizzled         (phase A)
//   43008..53504 Vt [16][328]                 (phase B, aliases Qs)
__global__ __launch_bounds__(256) void local_attn_kernel(
    const ushort_t* __restrict__ qb, const ushort_t* __restrict__ kb,
    const ushort_t* __restrict__ vtb, ushort_t* __restrict__ ob) {
    __shared__ __align__(16) char lds[53504];
    float* gs = (float*)(lds + 0);
    float* pg = (float*)(lds + 256);
    float* v0f = (float*)(lds + 512);
    float* k0f = (float*)(lds + 768);
    ushort_t* Kw = (ushort_t*)(lds + 1024);
    ushort_t* P = (ushort_t*)(lds + 1024);
    ushort_t* Qs = (ushort_t*)(lds + 43008);
    ushort_t* Vt = (ushort_t*)(lds + 43008);

    int qblk = blockIdx.x, h = blockIdx.y, b = blockIdx.z;
    int qbase = qblk * 64;
    int tid = threadIdx.x;
    int wave = tid >> 6, lane = tid & 63, quad = lane >> 4, l16 = lane & 15;
    int lrow = lane >> 3, scol = ((lane & 7) ^ lrow) * 8;
    int bh = b * HH + h;

    const ushort_t* qsrc = qb + ((size_t)bh * SS + qbase) * DH;
    const ushort_t* ksrc = kb + (size_t)bh * SS * DH;
    const ushort_t* vsrc = vtb + (size_t)bh * DH * SS;
    uintx4 zv = {0u, 0u, 0u, 0u};

    // stage Q (64x64) via global_load_lds, swizzled
#pragma unroll
    for (int ii = 0; ii < 2; ++ii) {
        int r0 = wave * 16 + ii * 8;
        load_lds16(qsrc + (size_t)(r0 + lrow) * DH + scol, lds + 43008 + r0 * 128);
    }
    // stage K window (320x64), zero-filled out of range (8-row blocks are uniformly in/out)
#pragma unroll
    for (int ii = 0; ii < 10; ++ii) {
        int r0 = wave * 80 + ii * 8;
        int s0 = qbase - 128 + r0;
        if (s0 >= 0 && s0 < SS) {
            load_lds16(ksrc + (size_t)(s0 + lrow) * DH + scol, lds + 1024 + r0 * 128);
        } else {
            *(uintx4*)(lds + 1024 + r0 * 128 + lane * 16) = zv;
        }
    }
    if (tid < 64) {
        k0f[tid] = bf2f(ksrc[tid]);                       // k[b,h,0,:]
        v0f[tid] = bf2f(vsrc[(size_t)tid * SS]);          // v[b,h,0,:]
    }
    __syncthreads();

    // global-column scores gs[qi] = q[qi] . k0   (swizzled Q reads)
    {
        int qi = tid >> 2, part = tid & 3;
        float a = 0.f;
#pragma unroll
        for (int j = 0; j < 16; ++j) {
            int d = part * 16 + j;
            int ch = (d >> 3) ^ (qi & 7);
            a += bf2f(Qs[qi * 64 + ch * 8 + (d & 7)]) * k0f[d];
        }
        a += __shfl_xor(a, 1, 64);
        a += __shfl_xor(a, 2, 64);
        if (part == 0) gs[qi] = a;
    }

    // QK^T: each wave owns 16 query rows x 320 keys
    int mrow = wave * 16;
    floatx4 sacc[20];
    floatx4 z4 = {0.f, 0.f, 0.f, 0.f};
#pragma unroll
    for (int t = 0; t < 20; ++t) sacc[t] = z4;
#pragma unroll
    for (int ks = 0; ks < 2; ++ks) {
        int swc = ((ks * 4 + quad) ^ (l16 & 7)) * 8;
        short8 a = *(const short8*)(&Qs[(mrow + l16) * 64 + swc]);
#pragma unroll
        for (int t = 0; t < 20; ++t) {
            short8 bfr = *(const short8*)(&Kw[(t * 16 + l16) * 64 + swc]);
            sacc[t] = __builtin_amdgcn_mfma_f32_16x16x32_bf16(a, bfr, sacc[t], 0, 0, 0);
        }
    }
    __syncthreads();   // Kw/Qs reads done; P may overwrite Kw; gs visible

    // mask + softmax + write P (bf16). rows: i = mrow + quad*4 + r
    const float NINF = -__builtin_inff();
#pragma unroll
    for (int r = 0; r < 4; ++r) {
        int i = mrow + quad * 4 + r;
#pragma unroll
        for (int t = 0; t < 20; ++t) {
            int j = t * 16 + l16;
            int kp = qbase - 128 + j;
            bool valid = (j >= i) && (j <= i + 256) && (kp >= 1) && (kp < SS);
            if (!valid) sacc[t][r] = NINF;
        }
        float gsv = gs[i];
        float m = gsv;
#pragma unroll
        for (int t = 0; t < 20; ++t) m = fmaxf(m, sacc[t][r]);
#pragma unroll
        for (int off = 1; off < 16; off <<= 1) m = fmaxf(m, __shfl_xor(m, off, 64));
        float sum = 0.f;
#pragma unroll
        for (int t = 0; t < 20; ++t) {
            float e = __expf(sacc[t][r] - m);
            sacc[t][r] = e;
            sum += e;
        }
#pragma unroll
        for (int off = 1; off < 16; off <<= 1) sum += __shfl_xor(sum, off, 64);
        float ge = __expf(gsv - m);
        sum += ge;
        float inv = 1.f / sum;
        if (l16 == 0) pg[i] = ge * inv;
#pragma unroll
        for (int t = 0; t < 20; ++t) P[i * 328 + t * 16 + l16] = f2bf(sacc[t][r] * inv);
    }

    // PV in four 16-dim passes (Vt 16 rows/pass, aliases dead Qs)
    for (int p = 0; p < 4; ++p) {
        __syncthreads();   // P writes done (p=0) / previous Vt reads done; Qs dead
        for (int c = tid; c < 640; c += 256) {
            int dd = c / 40, chv = c % 40;
            int s0 = qbase - 128 + chv * 8;
            uintx4 val = zv;
            if (s0 >= 0 && s0 < SS) val = *(const uintx4*)(vsrc + (size_t)(p * 16 + dd) * SS + s0);
            *(uintx4*)(Vt + dd * 328 + chv * 8) = val;
        }
        __syncthreads();
        floatx4 oacc = z4;
#pragma unroll
        for (int kt = 0; kt < 10; ++kt) {
            short8 a = *(const short8*)(&P[(mrow + l16) * 328 + kt * 32 + quad * 8]);
            short8 bfr = *(const short8*)(&Vt[l16 * 328 + kt * 32 + quad * 8]);
            oacc = __builtin_amdgcn_mfma_f32_16x16x32_bf16(a, bfr, oacc, 0, 0, 0);
        }
        int d = p * 16 + l16;
#pragma unroll
        for (int r = 0; r < 4; ++r) {
            int i = mrow + quad * 4 + r;
            float val = oacc[r] + pg[i] * v0f[d];
            ob[((size_t)b * SS + qbase + i) * DDIM + h * DH + d] = f2bf(val);
        }
    }
}

// ---------------- global-token full attention ----------------
__global__ __launch_bounds__(256) void global_attn_kernel(
    const float* __restrict__ qg, const ushort_t* __restrict__ kgb,
    const ushort_t* __restrict__ vgb, ushort_t* __restrict__ ob) {
    __shared__ float qgs[64];
    __shared__ float sc[SS];
    __shared__ float red[256];
    __shared__ float part[4][64];
    int h = blockIdx.x, b = blockIdx.y;
    int bh = b * HH + h;
    int tid = threadIdx.x;
    if (tid < 64) qgs[tid] = qg[b * DDIM + h * DH + tid];
    __syncthreads();
    const ushort_t* kr = kgb + (size_t)bh * SS * DH;
    for (int s = tid; s < SS; s += 256) {
        const ushort_t* row = kr + (size_t)s * DH;
        float a = 0.f;
#pragma unroll
        for (int c = 0; c < 8; ++c) {
            uintx4 pk = *(const uintx4*)(row + c * 8);
            const ushort_t* pe = (const ushort_t*)&pk;
#pragma unroll
            for (int j = 0; j < 8; ++j) a += qgs[c * 8 + j] * bf2f(pe[j]);
        }
        sc[s] = a;
    }
    __syncthreads();
    float m = -__builtin_inff();
    for (int s = tid; s < SS; s += 256) m = fmaxf(m, sc[s]);
    red[tid] = m;
    __syncthreads();
    for (int o = 128; o > 0; o >>= 1) {
        if (tid < o) red[tid] = fmaxf(red[tid], red[tid + o]);
        __syncthreads();
    }
    m = red[0];
    __syncthreads();
    float sum = 0.f;
    for (int s = tid; s < SS; s += 256) {
        float e = __expf(sc[s] - m);
        sc[s] = e;
        sum += e;
    }
    red[tid] = sum;
    __syncthreads();
    for (int o = 128; o > 0; o >>= 1) {
        if (tid < o) red[tid] += red[tid + o];
        __syncthreads();
    }
    float inv = 1.f / red[0];
    int d = tid & 63, ck = tid >> 6;
    const ushort_t* vr = vgb + (size_t)bh * SS * DH;
    float a = 0.f;
    for (int s = ck * 512; s < (ck + 1) * 512; ++s) a += sc[s] * bf2f(vr[(size_t)s * DH + d]);
    part[ck][d] = a;
    __syncthreads();
    if (tid < 64) {
        float go = (part[0][tid] + part[1][tid] + part[2][tid] + part[3][tid]) * inv;
        ob[(size_t)b * SS * DDIM + h * DH + tid] = f2bf(go);
    }
}

// ---------------- LayerNorm + output transpose ----------------
__global__ __launch_bounds__(256) void ln_kernel(const float* __restrict__ ypre, const float* __restrict__ g,
                                                 const float* __restrict__ be, float* __restrict__ out) {
    __shared__ float red[256];
    int m = blockIdx.x;          // b*2048 + s
    int b = m >> 11, s = m & 2047;
    int tid = threadIdx.x;
    const float* row = ypre + (size_t)m * DDIM;
    float v0 = row[tid], v1 = row[tid + 256], v2 = row[tid + 512], v3 = row[tid + 768];
    red[tid] = v0 + v1 + v2 + v3;
    __syncthreads();
    for (int o = 128; o > 0; o >>= 1) {
        if (tid < o) red[tid] += red[tid + o];
        __syncthreads();
    }
    float mu = red[0] * (1.f / 1024.f);
    __syncthreads();
    float d0 = v0 - mu, d1 = v1 - mu, d2 = v2 - mu, d3 = v3 - mu;
    red[tid] = d0 * d0 + d1 * d1 + d2 * d2 + d3 * d3;
    __syncthreads();
    for (int o = 128; o > 0; o >>= 1) {
        if (tid < o) red[tid] += red[tid + o];
        __syncthreads();
    }
    float rstd = rsqrtf(red[0] * (1.f / 1024.f) + 1e-5f);
    float* orow = out + (size_t)(s * BB + b) * DDIM;
    orow[tid] = d0 * rstd * g[tid] + be[tid];
    orow[tid + 256] = d1 * rstd * g[tid + 256] + be[tid + 256];
    orow[tid + 512] = d2 * rstd * g[tid + 512] + be[tid + 512];
    orow[tid + 768] = d3 * rstd * g[tid + 768] + be[tid + 768];
}

extern "C" void kernel_launch(void* const* d_in, const int* in_sizes, int n_in,
                              void* d_out, int out_size, void* d_ws, size_t ws_size,
                              hipStream_t stream) {
    const float* x   = (const float*)d_in[0];
    const float* Wq  = (const float*)d_in[2];  const float* bq  = (const float*)d_in[3];
    const float* Wk  = (const float*)d_in[4];  const float* bk  = (const float*)d_in[5];
    const float* Wv  = (const float*)d_in[6];  const float* bv  = (const float*)d_in[7];
    const float* Wqg = (const float*)d_in[8];  const float* bqg = (const float*)d_in[9];
    const float* Wkg = (const float*)d_in[10]; const float* bkg = (const float*)d_in[11];
    const float* Wvg = (const float*)d_in[12]; const float* bvg = (const float*)d_in[13];
    const float* Wo  = (const float*)d_in[14]; const float* bo  = (const float*)d_in[15];
    const float* lng = (const float*)d_in[16]; const float* lnb = (const float*)d_in[17];

    char* ws = (char*)d_ws;
    const size_t MAT = (size_t)BB * SS * DDIM;            // 8388608 elements
    size_t off = 0;
    ushort_t* wbf = (ushort_t*)(ws + off); off += (size_t)6 * 1024 * 1024 * 2;   // 12 MB
    size_t hoff = off;
    ushort_t* hbf = (ushort_t*)(ws + off); off += MAT * 2;                        // 16 MB
    ushort_t* qb  = (ushort_t*)(ws + off); off += MAT * 2;
    ushort_t* kb  = (ushort_t*)(ws + off); off += MAT * 2;
    ushort_t* vtb = (ushort_t*)(ws + off); off += MAT * 2;
    ushort_t* kgb = (ushort_t*)(ws + off); off += MAT * 2;
    ushort_t* vgb = (ushort_t*)(ws + off); off += MAT * 2;
    ushort_t* abf = (ushort_t*)(ws + off); off += MAT * 2;
    float* qgf    = (float*)(ws + off);    off += (size_t)BB * DDIM * 4;
    float* ypre   = (float*)(ws + hoff);   // aliases hbf+qb (32 MB, both dead by then)

    prep_kernel<<<dim3(58368), dim3(256), 0, stream>>>(x, Wq, Wk, Wv, Wkg, Wvg, Wo,
                                                       Wqg, bqg, hbf, wbf, qgf);
    qkv_gemm_kernel<<<dim3(64, 40), dim3(256), 0, stream>>>(hbf, wbf, bq, bk, bv, bkg, bvg,
                                                            qb, kb, vtb, kgb, vgb);
    local_attn_kernel<<<dim3(32, 16, 4), dim3(256), 0, stream>>>(qb, kb, vtb, abf);
    global_attn_kernel<<<dim3(16, 4), dim3(256), 0, stream>>>(qgf, kgb, vgb, abf);
    out_gemm_kernel<<<dim3(64, 8), dim3(256), 0, stream>>>(abf, wbf + (size_t)5 * 1024 * 1024,
                                                           bo, x, ypre);
    ln_kernel<<<dim3(8192), dim3(256), 0, stream>>>(ypre, lng, lnb, (float*)d_out);
}

// Round 5
// 380.965 us; speedup vs baseline: 1.0375x; 1.0375x over previous
//
#include <hip/hip_runtime.h>
#include <hip/hip_bf16.h>
#include <math.h>

#define BB 4
#define SS 2048
#define DDIM 1024
#define HH 16
#define DH 64

typedef unsigned short ushort_t;
typedef __attribute__((ext_vector_type(8))) short short8;
typedef __attribute__((ext_vector_type(4))) float floatx4;
typedef __attribute__((ext_vector_type(4))) unsigned int uintx4;

__device__ __forceinline__ float bf2f(ushort_t u) {
    unsigned int x = ((unsigned int)u) << 16;
    return __builtin_bit_cast(float, x);
}
__device__ __forceinline__ ushort_t f2bf(float f) {
    unsigned int x = __builtin_bit_cast(unsigned int, f);
    unsigned int r = (x + 0x7FFFu + ((x >> 16) & 1u)) >> 16;
    return (ushort_t)r;
}

__device__ __forceinline__ void load_lds16(const ushort_t* g, void* l) {
    __builtin_amdgcn_global_load_lds((const __attribute__((address_space(1))) void*)g,
                                     (__attribute__((address_space(3))) void*)l, 16, 0, 0);
}

// ---------------- fused prep: cast x, cast 6 weights, qg matvec ----------------
__global__ __launch_bounds__(256) void prep_kernel(
    const float* __restrict__ x,
    const float* __restrict__ w0, const float* __restrict__ w1, const float* __restrict__ w2,
    const float* __restrict__ w3, const float* __restrict__ w4, const float* __restrict__ w5,
    const float* __restrict__ Wqg, const float* __restrict__ bqg,
    ushort_t* __restrict__ hbf, ushort_t* __restrict__ wbf, float* __restrict__ qg) {
    int bid = blockIdx.x;
    int tid = threadIdx.x;
    if (bid < 32768) {
        int id = bid * 256 + tid;
        int d = id & (DDIM - 1);
        int s = (id >> 10) & (SS - 1);
        int b = id >> 21;
        hbf[id] = f2bf(x[(s * BB + b) * DDIM + d]);
    } else if (bid < 57344) {
        int id = (bid - 32768) * 256 + tid;
        int which = id >> 20;
        int r = id & 0xFFFFF;
        const float* src = which == 0 ? w0 : which == 1 ? w1 : which == 2 ? w2
                          : which == 3 ? w3 : which == 4 ? w4 : w5;
        wbf[id] = f2bf(src[r]);
    } else {
        int wave = ((bid - 57344) * 256 + tid) >> 6;
        int lane = tid & 63;
        int b = wave >> 10;
        int n = wave & 1023;
        const float* xr = x + b * DDIM;
        const float* wr = Wqg + n * DDIM;
        float acc = 0.f;
        for (int kk = lane; kk < DDIM; kk += 64) acc += xr[kk] * wr[kk];
        for (int off = 32; off > 0; off >>= 1) acc += __shfl_down(acc, off, 64);
        if (lane == 0) qg[b * DDIM + n] = (acc + bqg[n]) * 0.125f;
    }
}

// ---------------- fused qkv/kg/vg GEMM: 128x128 tile, global_load_lds, xor-swizzle ----------------
__global__ __launch_bounds__(256) void qkv_gemm_kernel(
    const ushort_t* __restrict__ hbf, const ushort_t* __restrict__ wbf,
    const float* __restrict__ bq, const float* __restrict__ bk, const float* __restrict__ bv,
    const float* __restrict__ bkg, const float* __restrict__ bvg,
    ushort_t* __restrict__ qb, ushort_t* __restrict__ kb, ushort_t* __restrict__ vtb,
    ushort_t* __restrict__ kgb, ushort_t* __restrict__ vgb) {
    __shared__ ushort_t As[128 * 64];
    __shared__ ushort_t Bs[128 * 64];
    int Mbase = blockIdx.x * 128;
    int Nbase = blockIdx.y * 128;
    int tid = threadIdx.x;
    int wave = tid >> 6, lane = tid & 63, quad = lane >> 4, l16 = lane & 15;
    int mbase = (wave & 1) * 64, nbase = (wave >> 1) * 64;
    int lrow = lane >> 3, scol = ((lane & 7) ^ lrow) * 8;

    const ushort_t* Ag = hbf + (size_t)(Mbase + wave * 32 + lrow) * DDIM + scol;
    const ushort_t* Bg = wbf + (size_t)(Nbase + wave * 32 + lrow) * DDIM + scol;

    floatx4 acc[4][4];
    floatx4 z4 = {0.f, 0.f, 0.f, 0.f};
#pragma unroll
    for (int i = 0; i < 4; ++i)
#pragma unroll
        for (int j = 0; j < 4; ++j) acc[i][j] = z4;

    for (int kk = 0; kk < DDIM; kk += 64) {
        __syncthreads();
#pragma unroll
        for (int j = 0; j < 4; ++j) {
            load_lds16(Ag + kk + (size_t)j * 8 * DDIM, &As[(wave * 32 + j * 8) * 64]);
            load_lds16(Bg + kk + (size_t)j * 8 * DDIM, &Bs[(wave * 32 + j * 8) * 64]);
        }
        __syncthreads();
#pragma unroll
        for (int ks = 0; ks < 2; ++ks) {
            int swc = ((ks * 4 + quad) ^ (l16 & 7)) * 8;
            short8 a[4], b[4];
#pragma unroll
            for (int mt = 0; mt < 4; ++mt)
                a[mt] = *(const short8*)(&As[(mbase + mt * 16 + l16) * 64 + swc]);
#pragma unroll
            for (int nt = 0; nt < 4; ++nt)
                b[nt] = *(const short8*)(&Bs[(nbase + nt * 16 + l16) * 64 + swc]);
#pragma unroll
            for (int mt = 0; mt < 4; ++mt)
#pragma unroll
                for (int nt = 0; nt < 4; ++nt)
                    acc[mt][nt] = __builtin_amdgcn_mfma_f32_16x16x32_bf16(a[mt], b[nt], acc[mt][nt], 0, 0, 0);
        }
    }

    int which = Nbase >> 10;
    float scale = (which == 0) ? 0.125f : 1.0f;
    const float* bias = which == 0 ? bq : which == 1 ? bk : which == 2 ? bv : which == 3 ? bkg : bvg;
#pragma unroll
    for (int nt = 0; nt < 4; ++nt) {
        int n = Nbase + nbase + nt * 16 + l16;
        int hd = n & 1023;
        int hh = hd >> 6, d = hd & 63;
        float bsv = bias[hd];
#pragma unroll
        for (int mt = 0; mt < 4; ++mt) {
#pragma unroll
            for (int r = 0; r < 4; ++r) {
                int m = Mbase + mbase + mt * 16 + quad * 4 + r;
                int b = m >> 11, s = m & 2047;
                float val = (acc[mt][nt][r] + bsv) * scale;
                ushort_t o = f2bf(val);
                if (which == 2) {
                    vtb[((size_t)(b * HH + hh) * DH + d) * SS + s] = o;
                } else {
                    ushort_t* dst = which == 0 ? qb : which == 1 ? kb : which == 3 ? kgb : vgb;
                    dst[((size_t)(b * HH + hh) * SS + s) * DH + d] = o;
                }
            }
        }
    }
}

// ---------------- output GEMM (attn @ Wo^T + bo + residual), 128x128 tile, swizzled ----------------
__global__ __launch_bounds__(256) void out_gemm_kernel(
    const ushort_t* __restrict__ abf, const ushort_t* __restrict__ wo,
    const float* __restrict__ bo, const float* __restrict__ x, float* __restrict__ ypre) {
    __shared__ ushort_t As[128 * 64];
    __shared__ ushort_t Bs[128 * 64];
    int Mbase = blockIdx.x * 128;
    int Nbase = blockIdx.y * 128;
    int tid = threadIdx.x;
    int wave = tid >> 6, lane = tid & 63, quad = lane >> 4, l16 = lane & 15;
    int mbase = (wave & 1) * 64, nbase = (wave >> 1) * 64;
    int lrow = lane >> 3, scol = ((lane & 7) ^ lrow) * 8;

    const ushort_t* Ag = abf + (size_t)(Mbase + wave * 32 + lrow) * DDIM + scol;
    const ushort_t* Bg = wo + (size_t)(Nbase + wave * 32 + lrow) * DDIM + scol;

    floatx4 acc[4][4];
    floatx4 z4 = {0.f, 0.f, 0.f, 0.f};
#pragma unroll
    for (int i = 0; i < 4; ++i)
#pragma unroll
        for (int j = 0; j < 4; ++j) acc[i][j] = z4;

    for (int kk = 0; kk < DDIM; kk += 64) {
        __syncthreads();
#pragma unroll
        for (int j = 0; j < 4; ++j) {
            load_lds16(Ag + kk + (size_t)j * 8 * DDIM, &As[(wave * 32 + j * 8) * 64]);
            load_lds16(Bg + kk + (size_t)j * 8 * DDIM, &Bs[(wave * 32 + j * 8) * 64]);
        }
        __syncthreads();
#pragma unroll
        for (int ks = 0; ks < 2; ++ks) {
            int swc = ((ks * 4 + quad) ^ (l16 & 7)) * 8;
            short8 a[4], b[4];
#pragma unroll
            for (int mt = 0; mt < 4; ++mt)
                a[mt] = *(const short8*)(&As[(mbase + mt * 16 + l16) * 64 + swc]);
#pragma unroll
            for (int nt = 0; nt < 4; ++nt)
                b[nt] = *(const short8*)(&Bs[(nbase + nt * 16 + l16) * 64 + swc]);
#pragma unroll
            for (int mt = 0; mt < 4; ++mt)
#pragma unroll
                for (int nt = 0; nt < 4; ++nt)
                    acc[mt][nt] = __builtin_amdgcn_mfma_f32_16x16x32_bf16(a[mt], b[nt], acc[mt][nt], 0, 0, 0);
        }
    }

#pragma unroll
    for (int nt = 0; nt < 4; ++nt) {
        int n = Nbase + nbase + nt * 16 + l16;
        float bsv = bo[n];
#pragma unroll
        for (int mt = 0; mt < 4; ++mt) {
#pragma unroll
            for (int r = 0; r < 4; ++r) {
                int m = Mbase + mbase + mt * 16 + quad * 4 + r;
                int b = m >> 11, s = m & 2047;
                ypre[(size_t)m * DDIM + n] = acc[mt][nt][r] + bsv + x[(size_t)(s * BB + b) * DDIM + n];
            }
        }
    }
}

// ---------------- local (windowed) attention, LDS-minimal ----------------
// block: (qblk, h, b); 64 queries; window = 320 keys; 256 threads.
// LDS arena 40960 B (4 blocks/CU): Kw [320][64] row-xor-swizzled (phase A),
// aliased by P [64][320] chunk-xor-swizzled (phase B, wave-private rows).
// Q and V fragments come DIRECTLY from global (16B contiguous runs) - no LDS.
__global__ __launch_bounds__(256) void local_attn_kernel(
    const ushort_t* __restrict__ qb, const ushort_t* __restrict__ kb,
    const ushort_t* __restrict__ vtb, ushort_t* __restrict__ ob) {
    __shared__ __align__(16) ushort_t arena[20480];   // 40960 B

    int qblk = blockIdx.x, h = blockIdx.y, b = blockIdx.z;
    int qbase = qblk * 64;
    int tid = threadIdx.x;
    int wave = tid >> 6, lane = tid & 63, quad = lane >> 4, l16 = lane & 15;
    int lrow = lane >> 3, scol = ((lane & 7) ^ lrow) * 8;
    int bh = b * HH + h;
    int mrow = wave * 16;

    const ushort_t* qsrc = qb + ((size_t)bh * SS + qbase) * DH;
    const ushort_t* ksrc = kb + (size_t)bh * SS * DH;
    const ushort_t* vsrc = vtb + (size_t)bh * DH * SS;
    uintx4 zv = {0u, 0u, 0u, 0u};
    floatx4 z4 = {0.f, 0.f, 0.f, 0.f};

    // ---- stage K window [320][64] via global_load_lds, row-xor-swizzled ----
#pragma unroll
    for (int ii = 0; ii < 10; ++ii) {
        int r0 = wave * 80 + ii * 8;
        int s0 = qbase - 128 + r0;
        if (s0 >= 0 && s0 < SS) {
            load_lds16(ksrc + (size_t)(s0 + lrow) * DH + scol, (char*)arena + r0 * 128);
        } else {
            *(uintx4*)((char*)arena + r0 * 128 + lane * 16) = zv;
        }
    }

    // ---- Q A-frags direct from global; gs = q . k0 in registers ----
    short8 aq[2];
    {
        uintx4 t0 = *(const uintx4*)(qsrc + (size_t)(mrow + l16) * DH + quad * 8);
        uintx4 t1 = *(const uintx4*)(qsrc + (size_t)(mrow + l16) * DH + 32 + quad * 8);
        aq[0] = __builtin_bit_cast(short8, t0);
        aq[1] = __builtin_bit_cast(short8, t1);
    }
    float gsp = 0.f;
    {
        uintx4 kk0 = *(const uintx4*)(ksrc + quad * 8);
        uintx4 kk1 = *(const uintx4*)(ksrc + 32 + quad * 8);
        const ushort_t* p0 = (const ushort_t*)&kk0;
        const ushort_t* p1 = (const ushort_t*)&kk1;
        const ushort_t* a0 = (const ushort_t*)&aq[0];
        const ushort_t* a1 = (const ushort_t*)&aq[1];
#pragma unroll
        for (int j = 0; j < 8; ++j)
            gsp += bf2f(a0[j]) * bf2f(p0[j]) + bf2f(a1[j]) * bf2f(p1[j]);
    }
    gsp += __shfl_xor(gsp, 16, 64);
    gsp += __shfl_xor(gsp, 32, 64);   // every lane: gs of row (mrow + l16)

    // v0 per d-tile (column 0 of transposed V)
    float v0r[4];
#pragma unroll
    for (int dt = 0; dt < 4; ++dt) v0r[dt] = bf2f(vsrc[(size_t)(dt * 16 + l16) * SS]);

    __syncthreads();   // K staged

    // ---- QK^T: wave owns 16 query rows x 320 keys ----
    floatx4 sacc[20];
#pragma unroll
    for (int t = 0; t < 20; ++t) sacc[t] = z4;
#pragma unroll
    for (int ks = 0; ks < 2; ++ks) {
        int swc = ((ks * 4 + quad) ^ (l16 & 7)) * 8;
#pragma unroll
        for (int t = 0; t < 20; ++t) {
            short8 bfr = *(const short8*)(&arena[(t * 16 + l16) * 64 + swc]);
            sacc[t] = __builtin_amdgcn_mfma_f32_16x16x32_bf16(aq[ks], bfr, sacc[t], 0, 0, 0);
        }
    }
    __syncthreads();   // all QK reads of Kw done; P may overwrite (wave-private rows)

    // ---- mask + softmax + P write (chunk-xor-swizzled, stride 320) ----
    const float NINF = -__builtin_inff();
    float pg_reg[4];
#pragma unroll
    for (int r = 0; r < 4; ++r) {
        int i = mrow + quad * 4 + r;
#pragma unroll
        for (int t = 0; t < 20; ++t) {
            int j = t * 16 + l16;
            int kp = qbase - 128 + j;
            bool valid = (j >= i - mrow ? true : false);
            valid = (j >= (i - mrow)) && (j <= (i - mrow) + 256) && (kp >= 1) && (kp < SS);
            // NOTE: window condition in absolute j vs row i within block: original used
            // (j >= i) && (j <= i+256) with i = row-in-block. i here is absolute-in-block row.
            int iblk = quad * 4 + r + mrow;
            valid = (j >= iblk) && (j <= iblk + 256) && (kp >= 1) && (kp < SS);
            if (!valid) sacc[t][r] = NINF;
        }
        float gsv = __shfl(gsp, quad * 4 + r, 64);
        float m = gsv;
#pragma unroll
        for (int t = 0; t < 20; ++t) m = fmaxf(m, sacc[t][r]);
#pragma unroll
        for (int off = 1; off < 16; off <<= 1) m = fmaxf(m, __shfl_xor(m, off, 64));
        float sum = 0.f;
#pragma unroll
        for (int t = 0; t < 20; ++t) {
            float e = __expf(sacc[t][r] - m);
            sacc[t][r] = e;
            sum += e;
        }
#pragma unroll
        for (int off = 1; off < 16; off <<= 1) sum += __shfl_xor(sum, off, 64);
        float ge = __expf(gsv - m);
        sum += ge;
        float inv = 1.f / sum;
        pg_reg[r] = ge * inv;
        int i7 = i & 7;
#pragma unroll
        for (int t = 0; t < 20; ++t) {
            int j = t * 16 + l16;
            int pc = (((j >> 3) ^ i7) << 3) + (j & 7);
            arena[i * 320 + pc] = f2bf(sacc[t][r] * inv);
        }
    }

    // ---- PV: A = P (wave-private LDS), B = V^T direct from global ----
    int swin = qbase - 128;
    floatx4 oacc[4];
#pragma unroll
    for (int dt = 0; dt < 4; ++dt) oacc[dt] = z4;
#pragma unroll
    for (int kt = 0; kt < 10; ++kt) {
        int i = mrow + l16;
        short8 ap = *(const short8*)(&arena[i * 320 + ((((kt * 4 + quad) ^ (l16 & 7))) << 3)]);
        int koff = swin + kt * 32 + quad * 8;
#pragma unroll
        for (int dt = 0; dt < 4; ++dt) {
            uintx4 bvv = *(const uintx4*)(vsrc + (ptrdiff_t)((dt * 16 + l16) * SS + koff));
            oacc[dt] = __builtin_amdgcn_mfma_f32_16x16x32_bf16(ap, __builtin_bit_cast(short8, bvv), oacc[dt], 0, 0, 0);
        }
    }

    // ---- store ----
#pragma unroll
    for (int dt = 0; dt < 4; ++dt) {
        int d = dt * 16 + l16;
#pragma unroll
        for (int r = 0; r < 4; ++r) {
            int i = mrow + quad * 4 + r;
            float val = oacc[dt][r] + pg_reg[r] * v0r[dt];
            ob[((size_t)b * SS + qbase + i) * DDIM + h * DH + d] = f2bf(val);
        }
    }
}

// ---------------- global-token full attention (1024 threads, vectorized) ----------------
__global__ __launch_bounds__(1024) void global_attn_kernel(
    const float* __restrict__ qg, const ushort_t* __restrict__ kgb,
    const ushort_t* __restrict__ vgb, ushort_t* __restrict__ ob) {
    __shared__ float qgs[64];
    __shared__ float sc[SS];
    __shared__ float red[1024];
    __shared__ float part[128][64];
    int h = blockIdx.x, b = blockIdx.y;
    int bh = b * HH + h;
    int tid = threadIdx.x;
    if (tid < 64) qgs[tid] = qg[b * DDIM + h * DH + tid];
    __syncthreads();
    const ushort_t* kr = kgb + (size_t)bh * SS * DH;
    for (int s = tid; s < SS; s += 1024) {
        const ushort_t* row = kr + (size_t)s * DH;
        float a = 0.f;
#pragma unroll
        for (int c = 0; c < 8; ++c) {
            uintx4 pk = *(const uintx4*)(row + c * 8);
            const ushort_t* pe = (const ushort_t*)&pk;
#pragma unroll
            for (int j = 0; j < 8; ++j) a += qgs[c * 8 + j] * bf2f(pe[j]);
        }
        sc[s] = a;
    }
    __syncthreads();
    float m = fmaxf(sc[tid], sc[tid + 1024]);
    red[tid] = m;
    __syncthreads();
    for (int o = 512; o > 0; o >>= 1) {
        if (tid < o) red[tid] = fmaxf(red[tid], red[tid + o]);
        __syncthreads();
    }
    m = red[0];
    __syncthreads();
    float e0 = __expf(sc[tid] - m), e1 = __expf(sc[tid + 1024] - m);
    sc[tid] = e0;
    sc[tid + 1024] = e1;
    red[tid] = e0 + e1;
    __syncthreads();
    for (int o = 512; o > 0; o >>= 1) {
        if (tid < o) red[tid] += red[tid + o];
        __syncthreads();
    }
    float inv = 1.f / red[0];
    // PV: strip = 16 s-rows, oct = 8 d's
    const ushort_t* vr = vgb + (size_t)bh * SS * DH;
    int strip = tid >> 3, oct = tid & 7;
    float acc[8];
#pragma unroll
    for (int j = 0; j < 8; ++j) acc[j] = 0.f;
    for (int ss2 = 0; ss2 < 16; ++ss2) {
        int s = strip * 16 + ss2;
        float e = sc[s];
        uintx4 pv = *(const uintx4*)(vr + (size_t)s * DH + oct * 8);
        const ushort_t* pe = (const ushort_t*)&pv;
#pragma unroll
        for (int j = 0; j < 8; ++j) acc[j] += e * bf2f(pe[j]);
    }
#pragma unroll
    for (int j = 0; j < 8; ++j) part[strip][oct * 8 + j] = acc[j];
    __syncthreads();
    for (int hh = 64; hh >= 1; hh >>= 1) {
        for (int idx = tid; idx < hh * 64; idx += 1024) {
            int st = idx >> 6, d = idx & 63;
            part[st][d] += part[st + hh][d];
        }
        __syncthreads();
    }
    if (tid < 64) ob[(size_t)b * SS * DDIM + h * DH + tid] = f2bf(part[0][tid] * inv);
}

// ---------------- LayerNorm + output transpose ----------------
__global__ __launch_bounds__(256) void ln_kernel(const float* __restrict__ ypre, const float* __restrict__ g,
                                                 const float* __restrict__ be, float* __restrict__ out) {
    __shared__ float red[256];
    int m = blockIdx.x;
    int b = m >> 11, s = m & 2047;
    int tid = threadIdx.x;
    const float* row = ypre + (size_t)m * DDIM;
    float v0 = row[tid], v1 = row[tid + 256], v2 = row[tid + 512], v3 = row[tid + 768];
    red[tid] = v0 + v1 + v2 + v3;
    __syncthreads();
    for (int o = 128; o > 0; o >>= 1) {
        if (tid < o) red[tid] += red[tid + o];
        __syncthreads();
    }
    float mu = red[0] * (1.f / 1024.f);
    __syncthreads();
    float d0 = v0 - mu, d1 = v1 - mu, d2 = v2 - mu, d3 = v3 - mu;
    red[tid] = d0 * d0 + d1 * d1 + d2 * d2 + d3 * d3;
    __syncthreads();
    for (int o = 128; o > 0; o >>= 1) {
        if (tid < o) red[tid] += red[tid + o];
        __syncthreads();
    }
    float rstd = rsqrtf(red[0] * (1.f / 1024.f) + 1e-5f);
    float* orow = out + (size_t)(s * BB + b) * DDIM;
    orow[tid] = d0 * rstd * g[tid] + be[tid];
    orow[tid + 256] = d1 * rstd * g[tid + 256] + be[tid + 256];
    orow[tid + 512] = d2 * rstd * g[tid + 512] + be[tid + 512];
    orow[tid + 768] = d3 * rstd * g[tid + 768] + be[tid + 768];
}

extern "C" void kernel_launch(void* const* d_in, const int* in_sizes, int n_in,
                              void* d_out, int out_size, void* d_ws, size_t ws_size,
                              hipStream_t stream) {
    const float* x   = (const float*)d_in[0];
    const float* Wq  = (const float*)d_in[2];  const float* bq  = (const float*)d_in[3];
    const float* Wk  = (const float*)d_in[4];  const float* bk  = (const float*)d_in[5];
    const float* Wv  = (const float*)d_in[6];  const float* bv  = (const float*)d_in[7];
    const float* Wqg = (const float*)d_in[8];  const float* bqg = (const float*)d_in[9];
    const float* Wkg = (const float*)d_in[10]; const float* bkg = (const float*)d_in[11];
    const float* Wvg = (const float*)d_in[12]; const float* bvg = (const float*)d_in[13];
    const float* Wo  = (const float*)d_in[14]; const float* bo  = (const float*)d_in[15];
    const float* lng = (const float*)d_in[16]; const float* lnb = (const float*)d_in[17];

    char* ws = (char*)d_ws;
    const size_t MAT = (size_t)BB * SS * DDIM;
    size_t off = 0;
    ushort_t* wbf = (ushort_t*)(ws + off); off += (size_t)6 * 1024 * 1024 * 2;
    size_t hoff = off;
    ushort_t* hbf = (ushort_t*)(ws + off); off += MAT * 2;
    ushort_t* qb  = (ushort_t*)(ws + off); off += MAT * 2;
    ushort_t* kb  = (ushort_t*)(ws + off); off += MAT * 2;
    ushort_t* vtb = (ushort_t*)(ws + off); off += MAT * 2;
    ushort_t* kgb = (ushort_t*)(ws + off); off += MAT * 2;
    ushort_t* vgb = (ushort_t*)(ws + off); off += MAT * 2;
    ushort_t* abf = (ushort_t*)(ws + off); off += MAT * 2;
    float* qgf    = (float*)(ws + off);    off += (size_t)BB * DDIM * 4;
    float* ypre   = (float*)(ws + hoff);   // aliases hbf+qb

    prep_kernel<<<dim3(58368), dim3(256), 0, stream>>>(x, Wq, Wk, Wv, Wkg, Wvg, Wo,
                                                       Wqg, bqg, hbf, wbf, qgf);
    qkv_gemm_kernel<<<dim3(64, 40), dim3(256), 0, stream>>>(hbf, wbf, bq, bk, bv, bkg, bvg,
                                                            qb, kb, vtb, kgb, vgb);
    local_attn_kernel<<<dim3(32, 16, 4), dim3(256), 0, stream>>>(qb, kb, vtb, abf);
    global_attn_kernel<<<dim3(16, 4), dim3(1024), 0, stream>>>(qgf, kgb, vgb, abf);
    out_gemm_kernel<<<dim3(64, 8), dim3(256), 0, stream>>>(abf, wbf + (size_t)5 * 1024 * 1024,
                                                           bo, x, ypre);
    ln_kernel<<<dim3(8192), dim3(256), 0, stream>>>(ypre, lng, lnb, (float*)d_out);
}

// Round 6
// 372.969 us; speedup vs baseline: 1.0597x; 1.0214x over previous
//
#include <hip/hip_runtime.h>
#include <hip/hip_bf16.h>
#include <math.h>

#define BB 4
#define SS 2048
#define DDIM 1024
#define HH 16
#define DH 64

typedef unsigned short ushort_t;
typedef __attribute__((ext_vector_type(8))) short short8;
typedef __attribute__((ext_vector_type(4))) float floatx4;
typedef __attribute__((ext_vector_type(4))) unsigned int uintx4;

__device__ __forceinline__ float bf2f(ushort_t u) {
    unsigned int x = ((unsigned int)u) << 16;
    return __builtin_bit_cast(float, x);
}
__device__ __forceinline__ ushort_t f2bf(float f) {
    unsigned int x = __builtin_bit_cast(unsigned int, f);
    unsigned int r = (x + 0x7FFFu + ((x >> 16) & 1u)) >> 16;
    return (ushort_t)r;
}

__device__ __forceinline__ void load_lds16(const ushort_t* g, void* l) {
    __builtin_amdgcn_global_load_lds((const __attribute__((address_space(1))) void*)g,
                                     (__attribute__((address_space(3))) void*)l, 16, 0, 0);
}

// ---------------- fused prep: cast x, cast 6 weights, qg matvec ----------------
__global__ __launch_bounds__(256) void prep_kernel(
    const float* __restrict__ x,
    const float* __restrict__ w0, const float* __restrict__ w1, const float* __restrict__ w2,
    const float* __restrict__ w3, const float* __restrict__ w4, const float* __restrict__ w5,
    const float* __restrict__ Wqg, const float* __restrict__ bqg,
    ushort_t* __restrict__ hbf, ushort_t* __restrict__ wbf, float* __restrict__ qg) {
    int bid = blockIdx.x;
    int tid = threadIdx.x;
    if (bid < 32768) {
        int id = bid * 256 + tid;
        int d = id & (DDIM - 1);
        int s = (id >> 10) & (SS - 1);
        int b = id >> 21;
        hbf[id] = f2bf(x[(s * BB + b) * DDIM + d]);
    } else if (bid < 57344) {
        int id = (bid - 32768) * 256 + tid;
        int which = id >> 20;
        int r = id & 0xFFFFF;
        const float* src = which == 0 ? w0 : which == 1 ? w1 : which == 2 ? w2
                          : which == 3 ? w3 : which == 4 ? w4 : w5;
        wbf[id] = f2bf(src[r]);
    } else {
        int wave = ((bid - 57344) * 256 + tid) >> 6;
        int lane = tid & 63;
        int b = wave >> 10;
        int n = wave & 1023;
        const float* xr = x + b * DDIM;
        const float* wr = Wqg + n * DDIM;
        float acc = 0.f;
        for (int kk = lane; kk < DDIM; kk += 64) acc += xr[kk] * wr[kk];
        for (int off = 32; off > 0; off >>= 1) acc += __shfl_down(acc, off, 64);
        if (lane == 0) qg[b * DDIM + n] = (acc + bqg[n]) * 0.125f;
    }
}

// ---------------- fused qkv/kg/vg GEMM: 128x128 tile, global_load_lds, xor-swizzle ----------------
__global__ __launch_bounds__(256) void qkv_gemm_kernel(
    const ushort_t* __restrict__ hbf, const ushort_t* __restrict__ wbf,
    const float* __restrict__ bq, const float* __restrict__ bk, const float* __restrict__ bv,
    const float* __restrict__ bkg, const float* __restrict__ bvg,
    ushort_t* __restrict__ qb, ushort_t* __restrict__ kb, ushort_t* __restrict__ vtb,
    ushort_t* __restrict__ kgb, ushort_t* __restrict__ vgb) {
    __shared__ ushort_t As[128 * 64];
    __shared__ ushort_t Bs[128 * 64];
    int Mbase = blockIdx.x * 128;
    int Nbase = blockIdx.y * 128;
    int tid = threadIdx.x;
    int wave = tid >> 6, lane = tid & 63, quad = lane >> 4, l16 = lane & 15;
    int mbase = (wave & 1) * 64, nbase = (wave >> 1) * 64;
    int lrow = lane >> 3, scol = ((lane & 7) ^ lrow) * 8;

    const ushort_t* Ag = hbf + (size_t)(Mbase + wave * 32 + lrow) * DDIM + scol;
    const ushort_t* Bg = wbf + (size_t)(Nbase + wave * 32 + lrow) * DDIM + scol;

    floatx4 acc[4][4];
    floatx4 z4 = {0.f, 0.f, 0.f, 0.f};
#pragma unroll
    for (int i = 0; i < 4; ++i)
#pragma unroll
        for (int j = 0; j < 4; ++j) acc[i][j] = z4;

    for (int kk = 0; kk < DDIM; kk += 64) {
        __syncthreads();
#pragma unroll
        for (int j = 0; j < 4; ++j) {
            load_lds16(Ag + kk + (size_t)j * 8 * DDIM, &As[(wave * 32 + j * 8) * 64]);
            load_lds16(Bg + kk + (size_t)j * 8 * DDIM, &Bs[(wave * 32 + j * 8) * 64]);
        }
        __syncthreads();
#pragma unroll
        for (int ks = 0; ks < 2; ++ks) {
            int swc = ((ks * 4 + quad) ^ (l16 & 7)) * 8;
            short8 a[4], b[4];
#pragma unroll
            for (int mt = 0; mt < 4; ++mt)
                a[mt] = *(const short8*)(&As[(mbase + mt * 16 + l16) * 64 + swc]);
#pragma unroll
            for (int nt = 0; nt < 4; ++nt)
                b[nt] = *(const short8*)(&Bs[(nbase + nt * 16 + l16) * 64 + swc]);
#pragma unroll
            for (int mt = 0; mt < 4; ++mt)
#pragma unroll
                for (int nt = 0; nt < 4; ++nt)
                    acc[mt][nt] = __builtin_amdgcn_mfma_f32_16x16x32_bf16(a[mt], b[nt], acc[mt][nt], 0, 0, 0);
        }
    }

    int which = Nbase >> 10;
    float scale = (which == 0) ? 0.125f : 1.0f;
    const float* bias = which == 0 ? bq : which == 1 ? bk : which == 2 ? bv : which == 3 ? bkg : bvg;
#pragma unroll
    for (int nt = 0; nt < 4; ++nt) {
        int n = Nbase + nbase + nt * 16 + l16;
        int hd = n & 1023;
        int hh = hd >> 6, d = hd & 63;
        float bsv = bias[hd];
#pragma unroll
        for (int mt = 0; mt < 4; ++mt) {
#pragma unroll
            for (int r = 0; r < 4; ++r) {
                int m = Mbase + mbase + mt * 16 + quad * 4 + r;
                int b = m >> 11, s = m & 2047;
                float val = (acc[mt][nt][r] + bsv) * scale;
                ushort_t o = f2bf(val);
                if (which == 2) {
                    vtb[((size_t)(b * HH + hh) * DH + d) * SS + s] = o;
                } else {
                    ushort_t* dst = which == 0 ? qb : which == 1 ? kb : which == 3 ? kgb : vgb;
                    dst[((size_t)(b * HH + hh) * SS + s) * DH + d] = o;
                }
            }
        }
    }
}

// ---------------- output GEMM (attn @ Wo^T + bo + residual), 128x128 tile, swizzled ----------------
__global__ __launch_bounds__(256) void out_gemm_kernel(
    const ushort_t* __restrict__ abf, const ushort_t* __restrict__ wo,
    const float* __restrict__ bo, const float* __restrict__ x, float* __restrict__ ypre) {
    __shared__ ushort_t As[128 * 64];
    __shared__ ushort_t Bs[128 * 64];
    int Mbase = blockIdx.x * 128;
    int Nbase = blockIdx.y * 128;
    int tid = threadIdx.x;
    int wave = tid >> 6, lane = tid & 63, quad = lane >> 4, l16 = lane & 15;
    int mbase = (wave & 1) * 64, nbase = (wave >> 1) * 64;
    int lrow = lane >> 3, scol = ((lane & 7) ^ lrow) * 8;

    const ushort_t* Ag = abf + (size_t)(Mbase + wave * 32 + lrow) * DDIM + scol;
    const ushort_t* Bg = wo + (size_t)(Nbase + wave * 32 + lrow) * DDIM + scol;

    floatx4 acc[4][4];
    floatx4 z4 = {0.f, 0.f, 0.f, 0.f};
#pragma unroll
    for (int i = 0; i < 4; ++i)
#pragma unroll
        for (int j = 0; j < 4; ++j) acc[i][j] = z4;

    for (int kk = 0; kk < DDIM; kk += 64) {
        __syncthreads();
#pragma unroll
        for (int j = 0; j < 4; ++j) {
            load_lds16(Ag + kk + (size_t)j * 8 * DDIM, &As[(wave * 32 + j * 8) * 64]);
            load_lds16(Bg + kk + (size_t)j * 8 * DDIM, &Bs[(wave * 32 + j * 8) * 64]);
        }
        __syncthreads();
#pragma unroll
        for (int ks = 0; ks < 2; ++ks) {
            int swc = ((ks * 4 + quad) ^ (l16 & 7)) * 8;
            short8 a[4], b[4];
#pragma unroll
            for (int mt = 0; mt < 4; ++mt)
                a[mt] = *(const short8*)(&As[(mbase + mt * 16 + l16) * 64 + swc]);
#pragma unroll
            for (int nt = 0; nt < 4; ++nt)
                b[nt] = *(const short8*)(&Bs[(nbase + nt * 16 + l16) * 64 + swc]);
#pragma unroll
            for (int mt = 0; mt < 4; ++mt)
#pragma unroll
                for (int nt = 0; nt < 4; ++nt)
                    acc[mt][nt] = __builtin_amdgcn_mfma_f32_16x16x32_bf16(a[mt], b[nt], acc[mt][nt], 0, 0, 0);
        }
    }

#pragma unroll
    for (int nt = 0; nt < 4; ++nt) {
        int n = Nbase + nbase + nt * 16 + l16;
        float bsv = bo[n];
#pragma unroll
        for (int mt = 0; mt < 4; ++mt) {
#pragma unroll
            for (int r = 0; r < 4; ++r) {
                int m = Mbase + mbase + mt * 16 + quad * 4 + r;
                int b = m >> 11, s = m & 2047;
                ypre[(size_t)m * DDIM + n] = acc[mt][nt][r] + bsv + x[(size_t)(s * BB + b) * DDIM + n];
            }
        }
    }
}

// ---------------- fused attention: local windows + global token ----------------
// grid (33, 16, 4). blockIdx.x < 32: local attention for 64 queries.
// blockIdx.x == 32: full attention for the global token (head h, batch b).
// Local LDS arena 61440 B (2 blocks/CU):
//   0..40960     K [320][64] row-xor-swizzled (phase A); P [64][320] chunk-xor-swizzled (phase B)
//   40960..61440 V [32][320] chunk-xor-swizzled, two 32-d passes
__global__ __launch_bounds__(256) void attn_kernel(
    const ushort_t* __restrict__ qb, const ushort_t* __restrict__ kb,
    const ushort_t* __restrict__ vtb, const float* __restrict__ qg,
    const ushort_t* __restrict__ kgb, const ushort_t* __restrict__ vgb,
    ushort_t* __restrict__ ob) {
    __shared__ __align__(16) char lds[61440];
    int h = blockIdx.y, b = blockIdx.z;
    int bh = b * HH + h;
    int tid = threadIdx.x;

    if (blockIdx.x == 32) {
        // ---------- global-token full attention ----------
        float* qgs = (float*)lds;                 // 64
        float* sc = (float*)(lds + 256);          // 2048
        float* red = (float*)(lds + 8448);        // 256
        float(*part)[64] = (float(*)[64])(lds + 9472);  // 32 x 64
        if (tid < 64) qgs[tid] = qg[b * DDIM + h * DH + tid];
        __syncthreads();
        const ushort_t* kr = kgb + (size_t)bh * SS * DH;
        for (int s = tid; s < SS; s += 256) {
            const ushort_t* row = kr + (size_t)s * DH;
            float a = 0.f;
#pragma unroll
            for (int c = 0; c < 8; ++c) {
                uintx4 pk = *(const uintx4*)(row + c * 8);
                const ushort_t* pe = (const ushort_t*)&pk;
#pragma unroll
                for (int j = 0; j < 8; ++j) a += qgs[c * 8 + j] * bf2f(pe[j]);
            }
            sc[s] = a;
        }
        __syncthreads();
        float m = -__builtin_inff();
        for (int s = tid; s < SS; s += 256) m = fmaxf(m, sc[s]);
        red[tid] = m;
        __syncthreads();
        for (int o = 128; o > 0; o >>= 1) {
            if (tid < o) red[tid] = fmaxf(red[tid], red[tid + o]);
            __syncthreads();
        }
        m = red[0];
        __syncthreads();
        float sum = 0.f;
        for (int s = tid; s < SS; s += 256) {
            float e = __expf(sc[s] - m);
            sc[s] = e;
            sum += e;
        }
        red[tid] = sum;
        __syncthreads();
        for (int o = 128; o > 0; o >>= 1) {
            if (tid < o) red[tid] += red[tid + o];
            __syncthreads();
        }
        float inv = 1.f / red[0];
        const ushort_t* vr = vgb + (size_t)bh * SS * DH;
        int strip = tid >> 3, oct = tid & 7;
        float acc[8];
#pragma unroll
        for (int j = 0; j < 8; ++j) acc[j] = 0.f;
        for (int ss2 = 0; ss2 < 64; ++ss2) {
            int s = strip * 64 + ss2;
            float e = sc[s];
            uintx4 pv = *(const uintx4*)(vr + (size_t)s * DH + oct * 8);
            const ushort_t* pe = (const ushort_t*)&pv;
#pragma unroll
            for (int j = 0; j < 8; ++j) acc[j] += e * bf2f(pe[j]);
        }
#pragma unroll
        for (int j = 0; j < 8; ++j) part[strip][oct * 8 + j] = acc[j];
        __syncthreads();
        for (int hh2 = 16; hh2 >= 1; hh2 >>= 1) {
            for (int idx = tid; idx < hh2 * 64; idx += 256) {
                int st = idx >> 6, d = idx & 63;
                part[st][d] += part[st + hh2][d];
            }
            __syncthreads();
        }
        if (tid < 64) ob[(size_t)b * SS * DDIM + h * DH + tid] = f2bf(part[0][tid] * inv);
        return;
    }

    // ---------- local windowed attention ----------
    int qblk = blockIdx.x;
    int qbase = qblk * 64;
    int wave = tid >> 6, lane = tid & 63, quad = lane >> 4, l16 = lane & 15;
    int lrow = lane >> 3, scol = ((lane & 7) ^ lrow) * 8;
    int mrow = wave * 16;
    int swin = qbase - 128;

    ushort_t* KP = (ushort_t*)lds;
    ushort_t* Vs = (ushort_t*)(lds + 40960);

    const ushort_t* qsrc = qb + ((size_t)bh * SS + qbase) * DH;
    const ushort_t* ksrc = kb + (size_t)bh * SS * DH;
    const ushort_t* vsrc = vtb + (size_t)bh * DH * SS;
    uintx4 zv = {0u, 0u, 0u, 0u};
    floatx4 z4 = {0.f, 0.f, 0.f, 0.f};

    // stage K [320][64] via global_load_lds, row-xor-swizzled
#pragma unroll
    for (int ii = 0; ii < 10; ++ii) {
        int r0 = wave * 80 + ii * 8;
        int s0 = swin + r0;
        if (s0 >= 0 && s0 < SS) {
            load_lds16(ksrc + (size_t)(s0 + lrow) * DH + scol, (char*)lds + r0 * 128);
        } else {
            *(uintx4*)((char*)lds + r0 * 128 + lane * 16) = zv;
        }
    }
    // stage V pass-0: d rows 0..31, [32][320] chunk-xor-swizzled
    for (int c = tid; c < 1280; c += 256) {
        int dd = c / 40, chv = c % 40;
        int s0 = swin + chv * 8;
        uintx4 val = zv;
        if (s0 >= 0 && s0 < SS) val = *(const uintx4*)(vsrc + (size_t)dd * SS + s0);
        *(uintx4*)(&Vs[dd * 320 + ((chv ^ (dd & 7)) << 3)]) = val;
    }

    // Q A-frags direct from global; gs = q . k0 in registers
    short8 aq[2];
    {
        uintx4 t0 = *(const uintx4*)(qsrc + (size_t)(mrow + l16) * DH + quad * 8);
        uintx4 t1 = *(const uintx4*)(qsrc + (size_t)(mrow + l16) * DH + 32 + quad * 8);
        aq[0] = __builtin_bit_cast(short8, t0);
        aq[1] = __builtin_bit_cast(short8, t1);
    }
    float gsp = 0.f;
    {
        uintx4 kk0 = *(const uintx4*)(ksrc + quad * 8);
        uintx4 kk1 = *(const uintx4*)(ksrc + 32 + quad * 8);
        const ushort_t* p0 = (const ushort_t*)&kk0;
        const ushort_t* p1 = (const ushort_t*)&kk1;
        const ushort_t* a0 = (const ushort_t*)&aq[0];
        const ushort_t* a1 = (const ushort_t*)&aq[1];
#pragma unroll
        for (int j = 0; j < 8; ++j)
            gsp += bf2f(a0[j]) * bf2f(p0[j]) + bf2f(a1[j]) * bf2f(p1[j]);
    }
    gsp += __shfl_xor(gsp, 16, 64);
    gsp += __shfl_xor(gsp, 32, 64);   // lane holds gs of row (mrow + l16)

    float v0r[4];
#pragma unroll
    for (int dt = 0; dt < 4; ++dt) v0r[dt] = bf2f(vsrc[(size_t)(dt * 16 + l16) * SS]);

    __syncthreads();   // K + V0 staged

    // QK^T: wave owns 16 query rows x 320 keys
    floatx4 sacc[20];
#pragma unroll
    for (int t = 0; t < 20; ++t) sacc[t] = z4;
#pragma unroll
    for (int ks = 0; ks < 2; ++ks) {
        int swc = ((ks * 4 + quad) ^ (l16 & 7)) * 8;
#pragma unroll
        for (int t = 0; t < 20; ++t) {
            short8 bfr = *(const short8*)(&KP[(t * 16 + l16) * 64 + swc]);
            sacc[t] = __builtin_amdgcn_mfma_f32_16x16x32_bf16(aq[ks], bfr, sacc[t], 0, 0, 0);
        }
    }
    __syncthreads();   // QK reads done; P may overwrite K region (wave-private rows)

    // mask + softmax + P write (chunk-xor-swizzled, stride 320)
    const float NINF = -__builtin_inff();
    float pg_reg[4];
#pragma unroll
    for (int r = 0; r < 4; ++r) {
        int i = mrow + quad * 4 + r;
#pragma unroll
        for (int t = 0; t < 20; ++t) {
            int j = t * 16 + l16;
            int kp = swin + j;
            bool valid = (j >= i) && (j <= i + 256) && (kp >= 1) && (kp < SS);
            if (!valid) sacc[t][r] = NINF;
        }
        float gsv = __shfl(gsp, quad * 4 + r, 64);
        float m = gsv;
#pragma unroll
        for (int t = 0; t < 20; ++t) m = fmaxf(m, sacc[t][r]);
#pragma unroll
        for (int off = 1; off < 16; off <<= 1) m = fmaxf(m, __shfl_xor(m, off, 64));
        float sum = 0.f;
#pragma unroll
        for (int t = 0; t < 20; ++t) {
            float e = __expf(sacc[t][r] - m);
            sacc[t][r] = e;
            sum += e;
        }
#pragma unroll
        for (int off = 1; off < 16; off <<= 1) sum += __shfl_xor(sum, off, 64);
        float ge = __expf(gsv - m);
        sum += ge;
        float inv = 1.f / sum;
        pg_reg[r] = ge * inv;
        int i7 = i & 7;
#pragma unroll
        for (int t = 0; t < 20; ++t) {
            int j = t * 16 + l16;
            int pc = (((j >> 3) ^ i7) << 3) + (j & 7);
            KP[i * 320 + pc] = f2bf(sacc[t][r] * inv);
        }
    }

    // PV: A = P (wave-private LDS rows), B = V (LDS), two 32-d passes
    floatx4 oacc[4];
#pragma unroll
    for (int dt = 0; dt < 4; ++dt) oacc[dt] = z4;
    for (int p = 0; p < 2; ++p) {
        if (p == 1) {
            __syncthreads();   // all waves done with V pass-0
            for (int c = tid; c < 1280; c += 256) {
                int dd = c / 40, chv = c % 40;
                int s0 = swin + chv * 8;
                uintx4 val = zv;
                if (s0 >= 0 && s0 < SS) val = *(const uintx4*)(vsrc + (size_t)(32 + dd) * SS + s0);
                *(uintx4*)(&Vs[dd * 320 + ((chv ^ (dd & 7)) << 3)]) = val;
            }
            __syncthreads();
        }
#pragma unroll
        for (int kt = 0; kt < 10; ++kt) {
            int swc = (((kt * 4 + quad) ^ (l16 & 7)) << 3);
            short8 ap = *(const short8*)(&KP[(mrow + l16) * 320 + swc]);
#pragma unroll
            for (int dt2 = 0; dt2 < 2; ++dt2) {
                short8 bfr = *(const short8*)(&Vs[(dt2 * 16 + l16) * 320 + swc]);
                oacc[p * 2 + dt2] = __builtin_amdgcn_mfma_f32_16x16x32_bf16(ap, bfr, oacc[p * 2 + dt2], 0, 0, 0);
            }
        }
    }

    // store
#pragma unroll
    for (int dt = 0; dt < 4; ++dt) {
        int d = dt * 16 + l16;
#pragma unroll
        for (int r = 0; r < 4; ++r) {
            int i = mrow + quad * 4 + r;
            float val = oacc[dt][r] + pg_reg[r] * v0r[dt];
            ob[((size_t)b * SS + qbase + i) * DDIM + h * DH + d] = f2bf(val);
        }
    }
}

// ---------------- LayerNorm + output transpose ----------------
__global__ __launch_bounds__(256) void ln_kernel(const float* __restrict__ ypre, const float* __restrict__ g,
                                                 const float* __restrict__ be, float* __restrict__ out) {
    __shared__ float red[256];
    int m = blockIdx.x;
    int b = m >> 11, s = m & 2047;
    int tid = threadIdx.x;
    const float* row = ypre + (size_t)m * DDIM;
    float v0 = row[tid], v1 = row[tid + 256], v2 = row[tid + 512], v3 = row[tid + 768];
    red[tid] = v0 + v1 + v2 + v3;
    __syncthreads();
    for (int o = 128; o > 0; o >>= 1) {
        if (tid < o) red[tid] += red[tid + o];
        __syncthreads();
    }
    float mu = red[0] * (1.f / 1024.f);
    __syncthreads();
    float d0 = v0 - mu, d1 = v1 - mu, d2 = v2 - mu, d3 = v3 - mu;
    red[tid] = d0 * d0 + d1 * d1 + d2 * d2 + d3 * d3;
    __syncthreads();
    for (int o = 128; o > 0; o >>= 1) {
        if (tid < o) red[tid] += red[tid + o];
        __syncthreads();
    }
    float rstd = rsqrtf(red[0] * (1.f / 1024.f) + 1e-5f);
    float* orow = out + (size_t)(s * BB + b) * DDIM;
    orow[tid] = d0 * rstd * g[tid] + be[tid];
    orow[tid + 256] = d1 * rstd * g[tid + 256] + be[tid + 256];
    orow[tid + 512] = d2 * rstd * g[tid + 512] + be[tid + 512];
    orow[tid + 768] = d3 * rstd * g[tid + 768] + be[tid + 768];
}

extern "C" void kernel_launch(void* const* d_in, const int* in_sizes, int n_in,
                              void* d_out, int out_size, void* d_ws, size_t ws_size,
                              hipStream_t stream) {
    const float* x   = (const float*)d_in[0];
    const float* Wq  = (const float*)d_in[2];  const float* bq  = (const float*)d_in[3];
    const float* Wk  = (const float*)d_in[4];  const float* bk  = (const float*)d_in[5];
    const float* Wv  = (const float*)d_in[6];  const float* bv  = (const float*)d_in[7];
    const float* Wqg = (const float*)d_in[8];  const float* bqg = (const float*)d_in[9];
    const float* Wkg = (const float*)d_in[10]; const float* bkg = (const float*)d_in[11];
    const float* Wvg = (const float*)d_in[12]; const float* bvg = (const float*)d_in[13];
    const float* Wo  = (const float*)d_in[14]; const float* bo  = (const float*)d_in[15];
    const float* lng = (const float*)d_in[16]; const float* lnb = (const float*)d_in[17];

    char* ws = (char*)d_ws;
    const size_t MAT = (size_t)BB * SS * DDIM;
    size_t off = 0;
    ushort_t* wbf = (ushort_t*)(ws + off); off += (size_t)6 * 1024 * 1024 * 2;
    size_t hoff = off;
    ushort_t* hbf = (ushort_t*)(ws + off); off += MAT * 2;
    ushort_t* qb  = (ushort_t*)(ws + off); off += MAT * 2;
    ushort_t* kb  = (ushort_t*)(ws + off); off += MAT * 2;
    ushort_t* vtb = (ushort_t*)(ws + off); off += MAT * 2;
    ushort_t* kgb = (ushort_t*)(ws + off); off += MAT * 2;
    ushort_t* vgb = (ushort_t*)(ws + off); off += MAT * 2;
    ushort_t* abf = (ushort_t*)(ws + off); off += MAT * 2;
    float* qgf    = (float*)(ws + off);    off += (size_t)BB * DDIM * 4;
    float* ypre   = (float*)(ws + hoff);   // aliases hbf+qb

    prep_kernel<<<dim3(58368), dim3(256), 0, stream>>>(x, Wq, Wk, Wv, Wkg, Wvg, Wo,
                                                       Wqg, bqg, hbf, wbf, qgf);
    qkv_gemm_kernel<<<dim3(64, 40), dim3(256), 0, stream>>>(hbf, wbf, bq, bk, bv, bkg, bvg,
                                                            qb, kb, vtb, kgb, vgb);
    attn_kernel<<<dim3(33, 16, 4), dim3(256), 0, stream>>>(qb, kb, vtb, qgf, kgb, vgb, abf);
    out_gemm_kernel<<<dim3(64, 8), dim3(256), 0, stream>>>(abf, wbf + (size_t)5 * 1024 * 1024,
                                                           bo, x, ypre);
    ln_kernel<<<dim3(8192), dim3(256), 0, stream>>>(ypre, lng, lnb, (float*)d_out);
}

// Round 9
// 364.038 us; speedup vs baseline: 1.0857x; 1.0245x over previous
//
#include <hip/hip_runtime.h>
#include <hip/hip_bf16.h>
#include <math.h>

#define BB 4
#define SS 2048
#define DDIM 1024
#define HH 16
#define DH 64

typedef unsigned short ushort_t;
typedef __attribute__((ext_vector_type(8))) short short8;
typedef __attribute__((ext_vector_type(4))) float floatx4;
typedef __attribute__((ext_vector_type(4))) unsigned int uintx4;
typedef __attribute__((ext_vector_type(2))) unsigned int uintx2;

__device__ __forceinline__ float bf2f(ushort_t u) {
    unsigned int x = ((unsigned int)u) << 16;
    return __builtin_bit_cast(float, x);
}
__device__ __forceinline__ ushort_t f2bf(float f) {
    unsigned int x = __builtin_bit_cast(unsigned int, f);
    unsigned int r = (x + 0x7FFFu + ((x >> 16) & 1u)) >> 16;
    return (ushort_t)r;
}

__device__ __forceinline__ void load_lds16(const ushort_t* g, void* l) {
    __builtin_amdgcn_global_load_lds((const __attribute__((address_space(1))) void*)g,
                                     (__attribute__((address_space(3))) void*)l, 16, 0, 0);
}

// ---------------- fused prep (vectorized x4): cast x, cast 6 weights, qg matvec ----------------
__global__ __launch_bounds__(256) void prep_kernel(
    const float* __restrict__ x,
    const float* __restrict__ w0, const float* __restrict__ w1, const float* __restrict__ w2,
    const float* __restrict__ w3, const float* __restrict__ w4, const float* __restrict__ w5,
    const float* __restrict__ Wqg, const float* __restrict__ bqg,
    ushort_t* __restrict__ hbf, ushort_t* __restrict__ wbf, float* __restrict__ qg) {
    int bid = blockIdx.x;
    int tid = threadIdx.x;
    if (bid < 8192) {
        // cast x [S,B,D] -> hbf [B,S,D], 4 elems/thread
        int base = (bid * 256 + tid) * 4;
        int d = base & (DDIM - 1);
        int s = (base >> 10) & (SS - 1);
        int b = base >> 21;
        floatx4 v = *(const floatx4*)(x + (size_t)(s * BB + b) * DDIM + d);
        uintx2 o;
        o.x = (unsigned int)f2bf(v.x) | ((unsigned int)f2bf(v.y) << 16);
        o.y = (unsigned int)f2bf(v.z) | ((unsigned int)f2bf(v.w) << 16);
        *(uintx2*)(hbf + base) = o;
    } else if (bid < 14336) {
        int base = ((bid - 8192) * 256 + tid) * 4;   // 6*1048576 elems
        int which = base >> 20;
        int r = base & 0xFFFFF;
        const float* src = which == 0 ? w0 : which == 1 ? w1 : which == 2 ? w2
                          : which == 3 ? w3 : which == 4 ? w4 : w5;
        floatx4 v = *(const floatx4*)(src + r);
        uintx2 o;
        o.x = (unsigned int)f2bf(v.x) | ((unsigned int)f2bf(v.y) << 16);
        o.y = (unsigned int)f2bf(v.z) | ((unsigned int)f2bf(v.w) << 16);
        *(uintx2*)(wbf + base) = o;
    } else {
        int wave = ((bid - 14336) * 256 + tid) >> 6;   // 0..4095
        int lane = tid & 63;
        int b = wave >> 10;
        int n = wave & 1023;
        const float* xr = x + b * DDIM;
        const float* wr = Wqg + n * DDIM;
        float acc = 0.f;
        for (int kk = lane; kk < DDIM; kk += 64) acc += xr[kk] * wr[kk];
        for (int off = 32; off > 0; off >>= 1) acc += __shfl_down(acc, off, 64);
        if (lane == 0) qg[b * DDIM + n] = (acc + bqg[n]) * 0.125f;
    }
}

// ---------------- fused qkv/kg/vg GEMM: 128x128 tile, global_load_lds, xor-swizzle ----------------
__global__ __launch_bounds__(256) void qkv_gemm_kernel(
    const ushort_t* __restrict__ hbf, const ushort_t* __restrict__ wbf,
    const float* __restrict__ bq, const float* __restrict__ bk, const float* __restrict__ bv,
    const float* __restrict__ bkg, const float* __restrict__ bvg,
    ushort_t* __restrict__ qb, ushort_t* __restrict__ kb, ushort_t* __restrict__ vtb,
    ushort_t* __restrict__ kgb, ushort_t* __restrict__ vgb) {
    __shared__ ushort_t As[128 * 64];
    __shared__ ushort_t Bs[128 * 64];
    int Mbase = blockIdx.x * 128;
    int Nbase = blockIdx.y * 128;
    int tid = threadIdx.x;
    int wave = tid >> 6, lane = tid & 63, quad = lane >> 4, l16 = lane & 15;
    int mbase = (wave & 1) * 64, nbase = (wave >> 1) * 64;
    int lrow = lane >> 3, scol = ((lane & 7) ^ lrow) * 8;

    const ushort_t* Ag = hbf + (size_t)(Mbase + wave * 32 + lrow) * DDIM + scol;
    const ushort_t* Bg = wbf + (size_t)(Nbase + wave * 32 + lrow) * DDIM + scol;

    floatx4 acc[4][4];
    floatx4 z4 = {0.f, 0.f, 0.f, 0.f};
#pragma unroll
    for (int i = 0; i < 4; ++i)
#pragma unroll
        for (int j = 0; j < 4; ++j) acc[i][j] = z4;

    for (int kk = 0; kk < DDIM; kk += 64) {
        __syncthreads();
#pragma unroll
        for (int j = 0; j < 4; ++j) {
            load_lds16(Ag + kk + (size_t)j * 8 * DDIM, &As[(wave * 32 + j * 8) * 64]);
            load_lds16(Bg + kk + (size_t)j * 8 * DDIM, &Bs[(wave * 32 + j * 8) * 64]);
        }
        __syncthreads();
#pragma unroll
        for (int ks = 0; ks < 2; ++ks) {
            int swc = ((ks * 4 + quad) ^ (l16 & 7)) * 8;
            short8 a[4], b[4];
#pragma unroll
            for (int mt = 0; mt < 4; ++mt)
                a[mt] = *(const short8*)(&As[(mbase + mt * 16 + l16) * 64 + swc]);
#pragma unroll
            for (int nt = 0; nt < 4; ++nt)
                b[nt] = *(const short8*)(&Bs[(nbase + nt * 16 + l16) * 64 + swc]);
#pragma unroll
            for (int mt = 0; mt < 4; ++mt)
#pragma unroll
                for (int nt = 0; nt < 4; ++nt)
                    acc[mt][nt] = __builtin_amdgcn_mfma_f32_16x16x32_bf16(a[mt], b[nt], acc[mt][nt], 0, 0, 0);
        }
    }

    int which = Nbase >> 10;
    float scale = (which == 0) ? 0.125f : 1.0f;
    const float* bias = which == 0 ? bq : which == 1 ? bk : which == 2 ? bv : which == 3 ? bkg : bvg;
#pragma unroll
    for (int nt = 0; nt < 4; ++nt) {
        int n = Nbase + nbase + nt * 16 + l16;
        int hd = n & 1023;
        int hh = hd >> 6, d = hd & 63;
        float bsv = bias[hd];
#pragma unroll
        for (int mt = 0; mt < 4; ++mt) {
#pragma unroll
            for (int r = 0; r < 4; ++r) {
                int m = Mbase + mbase + mt * 16 + quad * 4 + r;
                int b = m >> 11, s = m & 2047;
                float val = (acc[mt][nt][r] + bsv) * scale;
                ushort_t o = f2bf(val);
                if (which == 2) {
                    vtb[((size_t)(b * HH + hh) * DH + d) * SS + s] = o;
                } else {
                    ushort_t* dst = which == 0 ? qb : which == 1 ? kb : which == 3 ? kgb : vgb;
                    dst[((size_t)(b * HH + hh) * SS + s) * DH + d] = o;
                }
            }
        }
    }
}

// ---------------- output GEMM (attn @ Wo^T + bo + residual), fp32 output ----------------
__global__ __launch_bounds__(256) void out_gemm_kernel(
    const ushort_t* __restrict__ abf, const ushort_t* __restrict__ wo,
    const float* __restrict__ bo, const float* __restrict__ x, float* __restrict__ ypre) {
    __shared__ ushort_t As[128 * 64];
    __shared__ ushort_t Bs[128 * 64];
    int Mbase = blockIdx.x * 128;
    int Nbase = blockIdx.y * 128;
    int tid = threadIdx.x;
    int wave = tid >> 6, lane = tid & 63, quad = lane >> 4, l16 = lane & 15;
    int mbase = (wave & 1) * 64, nbase = (wave >> 1) * 64;
    int lrow = lane >> 3, scol = ((lane & 7) ^ lrow) * 8;

    const ushort_t* Ag = abf + (size_t)(Mbase + wave * 32 + lrow) * DDIM + scol;
    const ushort_t* Bg = wo + (size_t)(Nbase + wave * 32 + lrow) * DDIM + scol;

    floatx4 acc[4][4];
    floatx4 z4 = {0.f, 0.f, 0.f, 0.f};
#pragma unroll
    for (int i = 0; i < 4; ++i)
#pragma unroll
        for (int j = 0; j < 4; ++j) acc[i][j] = z4;

    for (int kk = 0; kk < DDIM; kk += 64) {
        __syncthreads();
#pragma unroll
        for (int j = 0; j < 4; ++j) {
            load_lds16(Ag + kk + (size_t)j * 8 * DDIM, &As[(wave * 32 + j * 8) * 64]);
            load_lds16(Bg + kk + (size_t)j * 8 * DDIM, &Bs[(wave * 32 + j * 8) * 64]);
        }
        __syncthreads();
#pragma unroll
        for (int ks = 0; ks < 2; ++ks) {
            int swc = ((ks * 4 + quad) ^ (l16 & 7)) * 8;
            short8 a[4], b[4];
#pragma unroll
            for (int mt = 0; mt < 4; ++mt)
                a[mt] = *(const short8*)(&As[(mbase + mt * 16 + l16) * 64 + swc]);
#pragma unroll
            for (int nt = 0; nt < 4; ++nt)
                b[nt] = *(const short8*)(&Bs[(nbase + nt * 16 + l16) * 64 + swc]);
#pragma unroll
            for (int mt = 0; mt < 4; ++mt)
#pragma unroll
                for (int nt = 0; nt < 4; ++nt)
                    acc[mt][nt] = __builtin_amdgcn_mfma_f32_16x16x32_bf16(a[mt], b[nt], acc[mt][nt], 0, 0, 0);
        }
    }

#pragma unroll
    for (int nt = 0; nt < 4; ++nt) {
        int n = Nbase + nbase + nt * 16 + l16;
        float bsv = bo[n];
#pragma unroll
        for (int mt = 0; mt < 4; ++mt) {
#pragma unroll
            for (int r = 0; r < 4; ++r) {
                int m = Mbase + mbase + mt * 16 + quad * 4 + r;
                int b = m >> 11, s = m & 2047;
                ypre[(size_t)m * DDIM + n] = acc[mt][nt][r] + bsv + x[(size_t)(s * BB + b) * DDIM + n];
            }
        }
    }
}

// ---------------- fused attention: local windows + global token ----------------
// RACE FIX: abf row s==0 is written ONLY by the global-token block (blockIdx.x==32).
// Local qblk-0 blocks skip their i==0 store (reference discards local row 0 anyway).
__global__ __launch_bounds__(256) void attn_kernel(
    const ushort_t* __restrict__ qb, const ushort_t* __restrict__ kb,
    const ushort_t* __restrict__ vtb, const float* __restrict__ qg,
    const ushort_t* __restrict__ kgb, const ushort_t* __restrict__ vgb,
    ushort_t* __restrict__ ob) {
    __shared__ __align__(16) char lds[61440];
    int h = blockIdx.y, b = blockIdx.z;
    int bh = b * HH + h;
    int tid = threadIdx.x;

    if (blockIdx.x == 32) {
        // ---------- global-token full attention ----------
        float* qgs = (float*)lds;
        float* sc = (float*)(lds + 256);
        float* red = (float*)(lds + 8448);
        float(*part)[64] = (float(*)[64])(lds + 9472);
        if (tid < 64) qgs[tid] = qg[b * DDIM + h * DH + tid];
        __syncthreads();
        const ushort_t* kr = kgb + (size_t)bh * SS * DH;
        for (int s = tid; s < SS; s += 256) {
            const ushort_t* row = kr + (size_t)s * DH;
            float a = 0.f;
#pragma unroll
            for (int c = 0; c < 8; ++c) {
                uintx4 pk = *(const uintx4*)(row + c * 8);
                const ushort_t* pe = (const ushort_t*)&pk;
#pragma unroll
                for (int j = 0; j < 8; ++j) a += qgs[c * 8 + j] * bf2f(pe[j]);
            }
            sc[s] = a;
        }
        __syncthreads();
        float m = -__builtin_inff();
        for (int s = tid; s < SS; s += 256) m = fmaxf(m, sc[s]);
        red[tid] = m;
        __syncthreads();
        for (int o = 128; o > 0; o >>= 1) {
            if (tid < o) red[tid] = fmaxf(red[tid], red[tid + o]);
            __syncthreads();
        }
        m = red[0];
        __syncthreads();
        float sum = 0.f;
        for (int s = tid; s < SS; s += 256) {
            float e = __expf(sc[s] - m);
            sc[s] = e;
            sum += e;
        }
        red[tid] = sum;
        __syncthreads();
        for (int o = 128; o > 0; o >>= 1) {
            if (tid < o) red[tid] += red[tid + o];
            __syncthreads();
        }
        float inv = 1.f / red[0];
        const ushort_t* vr = vgb + (size_t)bh * SS * DH;
        int strip = tid >> 3, oct = tid & 7;
        float acc[8];
#pragma unroll
        for (int j = 0; j < 8; ++j) acc[j] = 0.f;
        for (int ss2 = 0; ss2 < 64; ++ss2) {
            int s = strip * 64 + ss2;
            float e = sc[s];
            uintx4 pv = *(const uintx4*)(vr + (size_t)s * DH + oct * 8);
            const ushort_t* pe = (const ushort_t*)&pv;
#pragma unroll
            for (int j = 0; j < 8; ++j) acc[j] += e * bf2f(pe[j]);
        }
#pragma unroll
        for (int j = 0; j < 8; ++j) part[strip][oct * 8 + j] = acc[j];
        __syncthreads();
        for (int hh2 = 16; hh2 >= 1; hh2 >>= 1) {
            for (int idx = tid; idx < hh2 * 64; idx += 256) {
                int st = idx >> 6, d = idx & 63;
                part[st][d] += part[st + hh2][d];
            }
            __syncthreads();
        }
        if (tid < 64) ob[(size_t)b * SS * DDIM + h * DH + tid] = f2bf(part[0][tid] * inv);
        return;
    }

    // ---------- local windowed attention ----------
    int qblk = blockIdx.x;
    int qbase = qblk * 64;
    int wave = tid >> 6, lane = tid & 63, quad = lane >> 4, l16 = lane & 15;
    int lrow = lane >> 3, scol = ((lane & 7) ^ lrow) * 8;
    int mrow = wave * 16;
    int swin = qbase - 128;

    ushort_t* KP = (ushort_t*)lds;
    ushort_t* Vs = (ushort_t*)(lds + 40960);

    const ushort_t* qsrc = qb + ((size_t)bh * SS + qbase) * DH;
    const ushort_t* ksrc = kb + (size_t)bh * SS * DH;
    const ushort_t* vsrc = vtb + (size_t)bh * DH * SS;
    uintx4 zv = {0u, 0u, 0u, 0u};
    floatx4 z4 = {0.f, 0.f, 0.f, 0.f};

#pragma unroll
    for (int ii = 0; ii < 10; ++ii) {
        int r0 = wave * 80 + ii * 8;
        int s0 = swin + r0;
        if (s0 >= 0 && s0 < SS) {
            load_lds16(ksrc + (size_t)(s0 + lrow) * DH + scol, (char*)lds + r0 * 128);
        } else {
            *(uintx4*)((char*)lds + r0 * 128 + lane * 16) = zv;
        }
    }
    for (int c = tid; c < 1280; c += 256) {
        int dd = c / 40, chv = c % 40;
        int s0 = swin + chv * 8;
        uintx4 val = zv;
        if (s0 >= 0 && s0 < SS) val = *(const uintx4*)(vsrc + (size_t)dd * SS + s0);
        *(uintx4*)(&Vs[dd * 320 + ((chv ^ (dd & 7)) << 3)]) = val;
    }

    short8 aq[2];
    {
        uintx4 t0 = *(const uintx4*)(qsrc + (size_t)(mrow + l16) * DH + quad * 8);
        uintx4 t1 = *(const uintx4*)(qsrc + (size_t)(mrow + l16) * DH + 32 + quad * 8);
        aq[0] = __builtin_bit_cast(short8, t0);
        aq[1] = __builtin_bit_cast(short8, t1);
    }
    float gsp = 0.f;
    {
        uintx4 kk0 = *(const uintx4*)(ksrc + quad * 8);
        uintx4 kk1 = *(const uintx4*)(ksrc + 32 + quad * 8);
        const ushort_t* p0 = (const ushort_t*)&kk0;
        const ushort_t* p1 = (const ushort_t*)&kk1;
        const ushort_t* a0 = (const ushort_t*)&aq[0];
        const ushort_t* a1 = (const ushort_t*)&aq[1];
#pragma unroll
        for (int j = 0; j < 8; ++j)
            gsp += bf2f(a0[j]) * bf2f(p0[j]) + bf2f(a1[j]) * bf2f(p1[j]);
    }
    gsp += __shfl_xor(gsp, 16, 64);
    gsp += __shfl_xor(gsp, 32, 64);

    float v0r[4];
#pragma unroll
    for (int dt = 0; dt < 4; ++dt) v0r[dt] = bf2f(vsrc[(size_t)(dt * 16 + l16) * SS]);

    __syncthreads();

    floatx4 sacc[20];
#pragma unroll
    for (int t = 0; t < 20; ++t) sacc[t] = z4;
#pragma unroll
    for (int ks = 0; ks < 2; ++ks) {
        int swc = ((ks * 4 + quad) ^ (l16 & 7)) * 8;
#pragma unroll
        for (int t = 0; t < 20; ++t) {
            short8 bfr = *(const short8*)(&KP[(t * 16 + l16) * 64 + swc]);
            sacc[t] = __builtin_amdgcn_mfma_f32_16x16x32_bf16(aq[ks], bfr, sacc[t], 0, 0, 0);
        }
    }
    __syncthreads();

    const float NINF = -__builtin_inff();
    float pg_reg[4];
#pragma unroll
    for (int r = 0; r < 4; ++r) {
        int i = mrow + quad * 4 + r;
#pragma unroll
        for (int t = 0; t < 20; ++t) {
            int j = t * 16 + l16;
            int kp = swin + j;
            bool valid = (j >= i) && (j <= i + 256) && (kp >= 1) && (kp < SS);
            if (!valid) sacc[t][r] = NINF;
        }
        float gsv = __shfl(gsp, quad * 4 + r, 64);
        float m = gsv;
#pragma unroll
        for (int t = 0; t < 20; ++t) m = fmaxf(m, sacc[t][r]);
#pragma unroll
        for (int off = 1; off < 16; off <<= 1) m = fmaxf(m, __shfl_xor(m, off, 64));
        float sum = 0.f;
#pragma unroll
        for (int t = 0; t < 20; ++t) {
            float e = __expf(sacc[t][r] - m);
            sacc[t][r] = e;
            sum += e;
        }
#pragma unroll
        for (int off = 1; off < 16; off <<= 1) sum += __shfl_xor(sum, off, 64);
        float ge = __expf(gsv - m);
        sum += ge;
        float inv = 1.f / sum;
        pg_reg[r] = ge * inv;
        int i7 = i & 7;
#pragma unroll
        for (int t = 0; t < 20; ++t) {
            int j = t * 16 + l16;
            int pc = (((j >> 3) ^ i7) << 3) + (j & 7);
            KP[i * 320 + pc] = f2bf(sacc[t][r] * inv);
        }
    }

    floatx4 oacc[4];
#pragma unroll
    for (int dt = 0; dt < 4; ++dt) oacc[dt] = z4;
    for (int p = 0; p < 2; ++p) {
        if (p == 1) {
            __syncthreads();
            for (int c = tid; c < 1280; c += 256) {
                int dd = c / 40, chv = c % 40;
                int s0 = swin + chv * 8;
                uintx4 val = zv;
                if (s0 >= 0 && s0 < SS) val = *(const uintx4*)(vsrc + (size_t)(32 + dd) * SS + s0);
                *(uintx4*)(&Vs[dd * 320 + ((chv ^ (dd & 7)) << 3)]) = val;
            }
            __syncthreads();
        }
#pragma unroll
        for (int kt = 0; kt < 10; ++kt) {
            int swc = (((kt * 4 + quad) ^ (l16 & 7)) << 3);
            short8 ap = *(const short8*)(&KP[(mrow + l16) * 320 + swc]);
#pragma unroll
            for (int dt2 = 0; dt2 < 2; ++dt2) {
                short8 bfr = *(const short8*)(&Vs[(dt2 * 16 + l16) * 320 + swc]);
                oacc[p * 2 + dt2] = __builtin_amdgcn_mfma_f32_16x16x32_bf16(ap, bfr, oacc[p * 2 + dt2], 0, 0, 0);
            }
        }
    }

#pragma unroll
    for (int dt = 0; dt < 4; ++dt) {
        int d = dt * 16 + l16;
#pragma unroll
        for (int r = 0; r < 4; ++r) {
            int i = mrow + quad * 4 + r;
            if (qbase + i == 0) continue;   // row 0 owned by global-token block (race fix)
            float val = oacc[dt][r] + pg_reg[r] * v0r[dt];
            ob[((size_t)b * SS + qbase + i) * DDIM + h * DH + d] = f2bf(val);
        }
    }
}

// ---------------- LayerNorm (fp32 input) + output transpose, vectorized ----------------
__global__ __launch_bounds__(256) void ln_kernel(const float* __restrict__ ypre, const float* __restrict__ g,
                                                 const float* __restrict__ be, float* __restrict__ out) {
    __shared__ float red[256];
    int m = blockIdx.x;          // b*2048 + s
    int b = m >> 11, s = m & 2047;
    int tid = threadIdx.x;
    const float* row = ypre + (size_t)m * DDIM;
    floatx4 v = *(const floatx4*)(row + tid * 4);
    red[tid] = v.x + v.y + v.z + v.w;
    __syncthreads();
    for (int o = 128; o > 0; o >>= 1) {
        if (tid < o) red[tid] += red[tid + o];
        __syncthreads();
    }
    float mu = red[0] * (1.f / 1024.f);
    __syncthreads();
    float d0 = v.x - mu, d1 = v.y - mu, d2 = v.z - mu, d3 = v.w - mu;
    red[tid] = d0 * d0 + d1 * d1 + d2 * d2 + d3 * d3;
    __syncthreads();
    for (int o = 128; o > 0; o >>= 1) {
        if (tid < o) red[tid] += red[tid + o];
        __syncthreads();
    }
    float rstd = rsqrtf(red[0] * (1.f / 1024.f) + 1e-5f);
    const floatx4 gv = *(const floatx4*)(g + tid * 4);
    const floatx4 bv = *(const floatx4*)(be + tid * 4);
    floatx4 o4;
    o4.x = d0 * rstd * gv.x + bv.x;
    o4.y = d1 * rstd * gv.y + bv.y;
    o4.z = d2 * rstd * gv.z + bv.z;
    o4.w = d3 * rstd * gv.w + bv.w;
    *(floatx4*)(out + (size_t)(s * BB + b) * DDIM + tid * 4) = o4;
}

extern "C" void kernel_launch(void* const* d_in, const int* in_sizes, int n_in,
                              void* d_out, int out_size, void* d_ws, size_t ws_size,
                              hipStream_t stream) {
    const float* x   = (const float*)d_in[0];
    const float* Wq  = (const float*)d_in[2];  const float* bq  = (const float*)d_in[3];
    const float* Wk  = (const float*)d_in[4];  const float* bk  = (const float*)d_in[5];
    const float* Wv  = (const float*)d_in[6];  const float* bv  = (const float*)d_in[7];
    const float* Wqg = (const float*)d_in[8];  const float* bqg = (const float*)d_in[9];
    const float* Wkg = (const float*)d_in[10]; const float* bkg = (const float*)d_in[11];
    const float* Wvg = (const float*)d_in[12]; const float* bvg = (const float*)d_in[13];
    const float* Wo  = (const float*)d_in[14]; const float* bo  = (const float*)d_in[15];
    const float* lng = (const float*)d_in[16]; const float* lnb = (const float*)d_in[17];

    char* ws = (char*)d_ws;
    const size_t MAT = (size_t)BB * SS * DDIM;
    size_t off = 0;
    ushort_t* wbf = (ushort_t*)(ws + off); off += (size_t)6 * 1024 * 1024 * 2;
    size_t hoff = off;
    ushort_t* hbf = (ushort_t*)(ws + off); off += MAT * 2;
    ushort_t* qb  = (ushort_t*)(ws + off); off += MAT * 2;
    ushort_t* kb  = (ushort_t*)(ws + off); off += MAT * 2;
    ushort_t* vtb = (ushort_t*)(ws + off); off += MAT * 2;
    ushort_t* kgb = (ushort_t*)(ws + off); off += MAT * 2;
    ushort_t* vgb = (ushort_t*)(ws + off); off += MAT * 2;
    ushort_t* abf = (ushort_t*)(ws + off); off += MAT * 2;
    float* qgf    = (float*)(ws + off);    off += (size_t)BB * DDIM * 4;
    float* ypre   = (float*)(ws + hoff);   // 32 MB, aliases hbf+qb (both dead by out_gemm)

    prep_kernel<<<dim3(15360), dim3(256), 0, stream>>>(x, Wq, Wk, Wv, Wkg, Wvg, Wo,
                                                       Wqg, bqg, hbf, wbf, qgf);
    qkv_gemm_kernel<<<dim3(64, 40), dim3(256), 0, stream>>>(hbf, wbf, bq, bk, bv, bkg, bvg,
                                                            qb, kb, vtb, kgb, vgb);
    attn_kernel<<<dim3(33, 16, 4), dim3(256), 0, stream>>>(qb, kb, vtb, qgf, kgb, vgb, abf);
    out_gemm_kernel<<<dim3(64, 8), dim3(256), 0, stream>>>(abf, wbf + (size_t)5 * 1024 * 1024,
                                                           bo, x, ypre);
    ln_kernel<<<dim3(8192), dim3(256), 0, stream>>>(ypre, lng, lnb, (float*)d_out);
}